// Round 3
// baseline (2053.013 us; speedup 1.0000x reference)
//
#include <hip/hip_runtime.h>
#include <math.h>

#define H 128
#define NTA 16
#define NTC 16

__device__ __forceinline__ float sigmoid_f(float x) {
    return 1.0f / (1.0f + __expf(-x));
}

__device__ __forceinline__ float tanh_f(float x) {
    float t = __expf(-2.0f * fabsf(x));
    float r = (1.0f - t) / (1.0f + t);
    return copysignf(r, x);
}

// ---------------------------------------------------------------------------
// Kernel A: Xh[n][j] = sum_k h[n][k] * W_msg[j][k] + b_msg[j]   (all f32)
// block = 128 threads (j = column), NTA nodes per block.
// W row chunk in VGPRs; h rows broadcast-loaded (all lanes same address).
// ---------------------------------------------------------------------------
__global__ __launch_bounds__(128) void xh_kernel(
    const float* __restrict__ h, const float* __restrict__ Wm,
    const float* __restrict__ bm, float* __restrict__ Xh, int N)
{
    int j = threadIdx.x;
    int node0 = blockIdx.x * NTA;
    float acc[NTA];
#pragma unroll
    for (int i = 0; i < NTA; ++i) acc[i] = 0.f;

#pragma unroll
    for (int kc = 0; kc < 4; ++kc) {
        float w[32];
        const float4* wp = reinterpret_cast<const float4*>(Wm + (size_t)j * H + kc * 32);
#pragma unroll
        for (int q = 0; q < 8; ++q) {
            float4 v = wp[q];
            w[q*4+0] = v.x; w[q*4+1] = v.y; w[q*4+2] = v.z; w[q*4+3] = v.w;
        }
#pragma unroll
        for (int nn = 0; nn < NTA; ++nn) {
            int n = node0 + nn;
            int nc = n < N ? n : N - 1;  // clamp to keep loads in-bounds
            const float4* hp = reinterpret_cast<const float4*>(h + (size_t)nc * H + kc * 32);
#pragma unroll
            for (int q = 0; q < 8; ++q) {
                float4 v = hp[q];
                acc[nn] = fmaf(v.x, w[q*4+0], acc[nn]);
                acc[nn] = fmaf(v.y, w[q*4+1], acc[nn]);
                acc[nn] = fmaf(v.z, w[q*4+2], acc[nn]);
                acc[nn] = fmaf(v.w, w[q*4+3], acc[nn]);
            }
        }
    }

    float bias = bm[j];
#pragma unroll
    for (int nn = 0; nn < NTA; ++nn) {
        int n = node0 + nn;
        if (n < N) Xh[(size_t)n * H + j] = acc[nn] + bias;
    }
}

// ---------------------------------------------------------------------------
// Kernel B: per-edge gather + atomic segment-sum into messages (f32 in ws)
// 2 edges per 256-thread block; lane j handles one of 128 columns.
// ---------------------------------------------------------------------------
__global__ __launch_bounds__(256) void scatter_kernel(
    const float* __restrict__ Xh, const int* __restrict__ eidx,
    const int* __restrict__ etype, const float* __restrict__ emb,
    float* __restrict__ messages, int E, int N)
{
    int e = blockIdx.x * 2 + (threadIdx.x >> 7);
    int j = threadIdx.x & 127;
    if (e >= E) return;
    int src = eidx[e];
    int dst = eidx[E + e];
    int t = etype[e];
    t = t < 0 ? 0 : (t > 8 ? 8 : t);
    float v = Xh[(size_t)src * H + j] + emb[(size_t)t * H + j];
    atomicAdd(messages + (size_t)dst * H + j, v);
}

// ---------------------------------------------------------------------------
// Kernel C: GRU cell (f32 in, f32 out; overwrites d_out which held Xh).
// block = 384: t -> (gate g = t/128, column j = t%128); NTC nodes/block.
// ---------------------------------------------------------------------------
__global__ __launch_bounds__(384) void gru_kernel(
    const float* __restrict__ messages, const float* __restrict__ h,
    const float* __restrict__ Wih, const float* __restrict__ Whh,
    const float* __restrict__ bih, const float* __restrict__ bhh,
    const int* __restrict__ num_nodes_p, float* __restrict__ out, int N)
{
    __shared__ float S0[NTC][H];   // i_r + h_r
    __shared__ float S1[NTC][H];   // i_z + h_z
    __shared__ float S2i[NTC][H];  // i_n
    __shared__ float S2h[NTC][H];  // h_n

    int t = threadIdx.x;           // 0..383
    int g = t >> 7;
    int j = t & 127;
    int node0 = blockIdx.x * NTC;

    float acc_i[NTC], acc_h[NTC];
#pragma unroll
    for (int i = 0; i < NTC; ++i) { acc_i[i] = 0.f; acc_h[i] = 0.f; }

#pragma unroll
    for (int kc = 0; kc < 4; ++kc) {
        float wi[32], wh[32];
        const float4* wip = reinterpret_cast<const float4*>(Wih + (size_t)t * H + kc * 32);
        const float4* whp = reinterpret_cast<const float4*>(Whh + (size_t)t * H + kc * 32);
#pragma unroll
        for (int q = 0; q < 8; ++q) {
            float4 vi = wip[q];
            wi[q*4+0] = vi.x; wi[q*4+1] = vi.y; wi[q*4+2] = vi.z; wi[q*4+3] = vi.w;
            float4 vh = whp[q];
            wh[q*4+0] = vh.x; wh[q*4+1] = vh.y; wh[q*4+2] = vh.z; wh[q*4+3] = vh.w;
        }
#pragma unroll
        for (int nn = 0; nn < NTC; ++nn) {
            int n = node0 + nn;
            int nc = n < N ? n : N - 1;
            const float4* mp = reinterpret_cast<const float4*>(messages + (size_t)nc * H + kc * 32);
            const float4* hp = reinterpret_cast<const float4*>(h + (size_t)nc * H + kc * 32);
#pragma unroll
            for (int q = 0; q < 8; ++q) {
                float4 vm = mp[q];
                float4 vh = hp[q];
                acc_i[nn] = fmaf(vm.x, wi[q*4+0], acc_i[nn]);
                acc_i[nn] = fmaf(vm.y, wi[q*4+1], acc_i[nn]);
                acc_i[nn] = fmaf(vm.z, wi[q*4+2], acc_i[nn]);
                acc_i[nn] = fmaf(vm.w, wi[q*4+3], acc_i[nn]);
                acc_h[nn] = fmaf(vh.x, wh[q*4+0], acc_h[nn]);
                acc_h[nn] = fmaf(vh.y, wh[q*4+1], acc_h[nn]);
                acc_h[nn] = fmaf(vh.z, wh[q*4+2], acc_h[nn]);
                acc_h[nn] = fmaf(vh.w, wh[q*4+3], acc_h[nn]);
            }
        }
    }

    float bi = bih[t];
    float bh = bhh[t];

#pragma unroll
    for (int nn = 0; nn < NTC; ++nn) {
        float si = acc_i[nn] + bi;
        float sh = acc_h[nn] + bh;
        if (g == 0)      S0[nn][j] = si + sh;
        else if (g == 1) S1[nn][j] = si + sh;
        else           { S2i[nn][j] = si; S2h[nn][j] = sh; }
    }
    __syncthreads();

    int num_nodes = num_nodes_p[0];
    for (int idx = t; idx < NTC * H; idx += 384) {
        int nn = idx >> 7;
        int j2 = idx & 127;
        int n = node0 + nn;
        if (n >= N) continue;
        float r  = sigmoid_f(S0[nn][j2]);
        float z  = sigmoid_f(S1[nn][j2]);
        float nv = tanh_f(S2i[nn][j2] + r * S2h[nn][j2]);
        float hv = h[(size_t)n * H + j2];
        float o  = (1.0f - z) * nv + z * hv;
        out[(size_t)n * H + j2] = (n < num_nodes) ? o : 0.0f;
    }
}

extern "C" void kernel_launch(void* const* d_in, const int* in_sizes, int n_in,
                              void* d_out, int out_size, void* d_ws, size_t ws_size,
                              hipStream_t stream) {
    const float* h    = (const float*)d_in[0];
    const int*  eidx  = (const int*)d_in[1];
    const int*  etype = (const int*)d_in[2];
    const int*  numn  = (const int*)d_in[3];
    const float* Wm   = (const float*)d_in[4];
    const float* bm   = (const float*)d_in[5];
    const float* emb  = (const float*)d_in[6];
    const float* Wih  = (const float*)d_in[7];
    const float* Whh  = (const float*)d_in[8];
    const float* bih  = (const float*)d_in[9];
    const float* bhh  = (const float*)d_in[10];

    int N = in_sizes[0] / H;
    int E = in_sizes[2];

    float* messages = (float*)d_ws;   // N*H f32 (25.6 MB) — only ws use
    float* Xh       = (float*)d_out;  // d_out doubles as Xh scratch (f32)

    hipMemsetAsync(messages, 0, (size_t)N * H * sizeof(float), stream);

    xh_kernel<<<(N + NTA - 1) / NTA, 128, 0, stream>>>(h, Wm, bm, Xh, N);
    scatter_kernel<<<(E + 1) / 2, 256, 0, stream>>>(Xh, eidx, etype, emb, messages, E, N);
    gru_kernel<<<(N + NTC - 1) / NTC, 384, 0, stream>>>(messages, h, Wih, Whh, bih, bhh,
                                                        numn, (float*)d_out, N);
}

// Round 4
// 474.035 us; speedup vs baseline: 4.3309x; 4.3309x over previous
//
#include <hip/hip_runtime.h>
#include <math.h>

#define H 128
typedef unsigned int u32;
typedef __attribute__((ext_vector_type(8))) short short8;
typedef __attribute__((ext_vector_type(4))) float floatx4;

#define XS_STRIDE 136   // bf16 elems per padded row (128 + 8)
#define HS_STRIDE 132   // f32 elems per padded row (128 + 4), keeps 16B alignment

__device__ __forceinline__ float sigmoid_f(float x) {
    return 1.0f / (1.0f + __expf(-x));
}
__device__ __forceinline__ float tanh_f(float x) {
    float t = __expf(-2.0f * fabsf(x));
    float r = (1.0f - t) / (1.0f + t);
    return copysignf(r, x);
}
// f32 -> bf16 bits, round-to-nearest-even (finite inputs)
__device__ __forceinline__ unsigned short f2bf(float x) {
    u32 u = __float_as_uint(x);
    return (unsigned short)((u + 0x7fffu + ((u >> 16) & 1u)) >> 16);
}

// ---------------------------------------------------------------------------
// Convert the three weight matrices to bf16 once per call (into ws).
// ---------------------------------------------------------------------------
__global__ __launch_bounds__(256) void convert_w_kernel(
    const float* __restrict__ Wih, const float* __restrict__ Whh,
    const float* __restrict__ Wm,
    unsigned short* __restrict__ Wihb, unsigned short* __restrict__ Whhb,
    unsigned short* __restrict__ Wmb)
{
    int i = blockIdx.x * 256 + threadIdx.x;
    if (i < 3 * H * H) {
        Wihb[i] = f2bf(Wih[i]);
        Whhb[i] = f2bf(Whh[i]);
    }
    if (i < H * H) Wmb[i] = f2bf(Wm[i]);
}

// ---------------------------------------------------------------------------
// Kernel A (MFMA): Xh[n][c] = sum_k h[n][k] * Wm[c][k] + bm[c]
// 256 threads = 4 waves; each wave owns a 16-node M-tile (64 nodes/block).
// h staged to LDS as bf16 (padded rows); A-frags in regs across the N-loop.
// ---------------------------------------------------------------------------
__global__ __launch_bounds__(256) void xh_mfma_kernel(
    const float* __restrict__ h, const unsigned short* __restrict__ Wmb,
    const float* __restrict__ bm, float* __restrict__ Xh, int N)
{
    __shared__ unsigned short hsb[64 * XS_STRIDE];

    int tid = threadIdx.x;
    int node0 = blockIdx.x * 64;

    // stage: 64 rows x 16 chunks of 8 floats
    for (int c = tid; c < 1024; c += 256) {
        int r = c >> 4;
        int k8 = (c & 15) << 3;
        int n = node0 + r;
        int nc = n < N ? n : N - 1;
        const float4* hp = (const float4*)(h + (size_t)nc * H + k8);
        float4 a = hp[0], b = hp[1];
        short8 v;
        v[0] = (short)f2bf(a.x); v[1] = (short)f2bf(a.y);
        v[2] = (short)f2bf(a.z); v[3] = (short)f2bf(a.w);
        v[4] = (short)f2bf(b.x); v[5] = (short)f2bf(b.y);
        v[6] = (short)f2bf(b.z); v[7] = (short)f2bf(b.w);
        *(short8*)(&hsb[r * XS_STRIDE + k8]) = v;
    }
    __syncthreads();

    int lane = tid & 63;
    int wv = tid >> 6;
    int am = lane & 15;    // A m-index / B n-index
    int aq = lane >> 4;    // quad

    short8 ah[4];
    int arow = wv * 16 + am;
#pragma unroll
    for (int kc = 0; kc < 4; ++kc)
        ah[kc] = *(const short8*)(&hsb[arow * XS_STRIDE + kc * 32 + aq * 8]);

    floatx4 zero = {0.f, 0.f, 0.f, 0.f};
#pragma unroll
    for (int j = 0; j < 8; ++j) {
        floatx4 acc = zero;
#pragma unroll
        for (int kc = 0; kc < 4; ++kc) {
            int ko = kc * 32 + aq * 8;
            short8 b = *(const short8*)(Wmb + (size_t)(j * 16 + am) * H + ko);
            acc = __builtin_amdgcn_mfma_f32_16x16x32_bf16(ah[kc], b, acc, 0, 0, 0);
        }
        int c = j * 16 + am;
        float bias = bm[c];
#pragma unroll
        for (int q = 0; q < 4; ++q) {
            int node = node0 + wv * 16 + aq * 4 + q;
            if (node < N) Xh[(size_t)node * H + c] = acc[q] + bias;
        }
    }
}

// ---------------------------------------------------------------------------
// Kernel B: per-edge gather + atomic segment-sum into messages (f32 in ws)
// ---------------------------------------------------------------------------
__global__ __launch_bounds__(256) void scatter_kernel(
    const float* __restrict__ Xh, const int* __restrict__ eidx,
    const int* __restrict__ etype, const float* __restrict__ emb,
    float* __restrict__ messages, int E, int N)
{
    int e = blockIdx.x * 2 + (threadIdx.x >> 7);
    int j = threadIdx.x & 127;
    if (e >= E) return;
    int src = eidx[e];
    int dst = eidx[E + e];
    int t = etype[e];
    t = t < 0 ? 0 : (t > 8 ? 8 : t);
    float v = Xh[(size_t)src * H + j] + emb[(size_t)t * H + j];
    atomicAdd(messages + (size_t)dst * H + j, v);
}

// ---------------------------------------------------------------------------
// Kernel C (MFMA): fused GRU.
// Per wave: 16-node M-tile. For each gate-row triple tile j (rows j16, j16+128,
// j16+256 of W_ih / W_hh): 6 accumulators (Gi/Gh x r/z/n), epilogue in regs.
// ---------------------------------------------------------------------------
__global__ __launch_bounds__(256) void gru_mfma_kernel(
    const float* __restrict__ messages, const float* __restrict__ h,
    const unsigned short* __restrict__ Wihb, const unsigned short* __restrict__ Whhb,
    const float* __restrict__ bih, const float* __restrict__ bhh,
    const int* __restrict__ numn, float* __restrict__ out, int N)
{
    __shared__ unsigned short xs[64 * XS_STRIDE];
    __shared__ unsigned short hsb[64 * XS_STRIDE];
    __shared__ float hsf[64 * HS_STRIDE];

    int tid = threadIdx.x;
    int node0 = blockIdx.x * 64;

    for (int c = tid; c < 1024; c += 256) {
        int r = c >> 4;
        int k8 = (c & 15) << 3;
        int n = node0 + r;
        int nc = n < N ? n : N - 1;
        const float4* mp = (const float4*)(messages + (size_t)nc * H + k8);
        float4 m0 = mp[0], m1 = mp[1];
        const float4* hp = (const float4*)(h + (size_t)nc * H + k8);
        float4 h0 = hp[0], h1 = hp[1];
        short8 xv, hv;
        xv[0] = (short)f2bf(m0.x); xv[1] = (short)f2bf(m0.y);
        xv[2] = (short)f2bf(m0.z); xv[3] = (short)f2bf(m0.w);
        xv[4] = (short)f2bf(m1.x); xv[5] = (short)f2bf(m1.y);
        xv[6] = (short)f2bf(m1.z); xv[7] = (short)f2bf(m1.w);
        hv[0] = (short)f2bf(h0.x); hv[1] = (short)f2bf(h0.y);
        hv[2] = (short)f2bf(h0.z); hv[3] = (short)f2bf(h0.w);
        hv[4] = (short)f2bf(h1.x); hv[5] = (short)f2bf(h1.y);
        hv[6] = (short)f2bf(h1.z); hv[7] = (short)f2bf(h1.w);
        *(short8*)(&xs[r * XS_STRIDE + k8]) = xv;
        *(short8*)(&hsb[r * XS_STRIDE + k8]) = hv;
        *(float4*)(&hsf[r * HS_STRIDE + k8]) = h0;
        *(float4*)(&hsf[r * HS_STRIDE + k8 + 4]) = h1;
    }
    __syncthreads();

    int lane = tid & 63;
    int wv = tid >> 6;
    int am = lane & 15;
    int aq = lane >> 4;

    short8 ax[4], ahf[4];
    int arow = wv * 16 + am;
#pragma unroll
    for (int kc = 0; kc < 4; ++kc) {
        ax[kc]  = *(const short8*)(&xs[arow * XS_STRIDE + kc * 32 + aq * 8]);
        ahf[kc] = *(const short8*)(&hsb[arow * XS_STRIDE + kc * 32 + aq * 8]);
    }

    int num_nodes = numn[0];
    floatx4 zero = {0.f, 0.f, 0.f, 0.f};

#pragma unroll
    for (int j = 0; j < 8; ++j) {
        floatx4 aIr = zero, aHr = zero, aIz = zero, aHz = zero, aIn = zero, aHn = zero;
        size_t row_r = (size_t)(j * 16 + am) * H;
        size_t row_z = (size_t)(128 + j * 16 + am) * H;
        size_t row_n = (size_t)(256 + j * 16 + am) * H;
#pragma unroll
        for (int kc = 0; kc < 4; ++kc) {
            int ko = kc * 32 + aq * 8;
            short8 bir = *(const short8*)(Wihb + row_r + ko);
            short8 bhr = *(const short8*)(Whhb + row_r + ko);
            short8 biz = *(const short8*)(Wihb + row_z + ko);
            short8 bhz = *(const short8*)(Whhb + row_z + ko);
            short8 bin = *(const short8*)(Wihb + row_n + ko);
            short8 bhn = *(const short8*)(Whhb + row_n + ko);
            aIr = __builtin_amdgcn_mfma_f32_16x16x32_bf16(ax[kc],  bir, aIr, 0, 0, 0);
            aHr = __builtin_amdgcn_mfma_f32_16x16x32_bf16(ahf[kc], bhr, aHr, 0, 0, 0);
            aIz = __builtin_amdgcn_mfma_f32_16x16x32_bf16(ax[kc],  biz, aIz, 0, 0, 0);
            aHz = __builtin_amdgcn_mfma_f32_16x16x32_bf16(ahf[kc], bhz, aHz, 0, 0, 0);
            aIn = __builtin_amdgcn_mfma_f32_16x16x32_bf16(ax[kc],  bin, aIn, 0, 0, 0);
            aHn = __builtin_amdgcn_mfma_f32_16x16x32_bf16(ahf[kc], bhn, aHn, 0, 0, 0);
        }
        int c = j * 16 + am;
        float b_ir = bih[c],       b_hr = bhh[c];
        float b_iz = bih[128 + c], b_hz = bhh[128 + c];
        float b_in = bih[256 + c], b_hn = bhh[256 + c];
#pragma unroll
        for (int q = 0; q < 4; ++q) {
            int m = aq * 4 + q;
            int node = node0 + wv * 16 + m;
            if (node < N) {
                float r  = sigmoid_f(aIr[q] + b_ir + aHr[q] + b_hr);
                float z  = sigmoid_f(aIz[q] + b_iz + aHz[q] + b_hz);
                float nv = tanh_f((aIn[q] + b_in) + r * (aHn[q] + b_hn));
                float hv = hsf[(wv * 16 + m) * HS_STRIDE + c];
                float o  = (1.0f - z) * nv + z * hv;
                out[(size_t)node * H + c] = (node < num_nodes) ? o : 0.0f;
            }
        }
    }
}

extern "C" void kernel_launch(void* const* d_in, const int* in_sizes, int n_in,
                              void* d_out, int out_size, void* d_ws, size_t ws_size,
                              hipStream_t stream) {
    const float* h    = (const float*)d_in[0];
    const int*  eidx  = (const int*)d_in[1];
    const int*  etype = (const int*)d_in[2];
    const int*  numn  = (const int*)d_in[3];
    const float* Wm   = (const float*)d_in[4];
    const float* bm   = (const float*)d_in[5];
    const float* emb  = (const float*)d_in[6];
    const float* Wih  = (const float*)d_in[7];
    const float* Whh  = (const float*)d_in[8];
    const float* bih  = (const float*)d_in[9];
    const float* bhh  = (const float*)d_in[10];

    int N = in_sizes[0] / H;
    int E = in_sizes[2];

    float* messages = (float*)d_ws;                             // N*H f32
    unsigned short* Wihb = (unsigned short*)(messages + (size_t)N * H);
    unsigned short* Whhb = Wihb + 3 * H * H;
    unsigned short* Wmb  = Whhb + 3 * H * H;
    float* Xh = (float*)d_out;                                  // scratch in d_out

    hipMemsetAsync(messages, 0, (size_t)N * H * sizeof(float), stream);

    convert_w_kernel<<<(3 * H * H + 255) / 256, 256, 0, stream>>>(
        Wih, Whh, Wm, Wihb, Whhb, Wmb);

    int nblk = (N + 63) / 64;
    xh_mfma_kernel<<<nblk, 256, 0, stream>>>(h, Wmb, bm, Xh, N);
    scatter_kernel<<<(E + 1) / 2, 256, 0, stream>>>(Xh, eidx, etype, emb, messages, E, N);
    gru_mfma_kernel<<<nblk, 256, 0, stream>>>(messages, h, Wihb, Whhb, bih, bhh,
                                              numn, (float*)d_out, N);
}

// Round 5
// 460.133 us; speedup vs baseline: 4.4618x; 1.0302x over previous
//
#include <hip/hip_runtime.h>
#include <math.h>

#define H 128
typedef unsigned int u32;
typedef __attribute__((ext_vector_type(8))) short short8;
typedef __attribute__((ext_vector_type(4))) float floatx4;

#define XS_STRIDE 136   // bf16 elems per padded row (128 + 8)
#define HS_STRIDE 132   // f32 elems per padded row (128 + 4), keeps 16B alignment

__device__ __forceinline__ float sigmoid_f(float x) {
    return 1.0f / (1.0f + __expf(-x));
}
__device__ __forceinline__ float tanh_f(float x) {
    float t = __expf(-2.0f * fabsf(x));
    float r = (1.0f - t) / (1.0f + t);
    return copysignf(r, x);
}
// f32 -> bf16 bits, round-to-nearest-even (finite inputs)
__device__ __forceinline__ unsigned short f2bf(float x) {
    u32 u = __float_as_uint(x);
    return (unsigned short)((u + 0x7fffu + ((u >> 16) & 1u)) >> 16);
}

// ---------------------------------------------------------------------------
// Convert the three weight matrices to bf16 once per call (into ws).
// ---------------------------------------------------------------------------
__global__ __launch_bounds__(256) void convert_w_kernel(
    const float* __restrict__ Wih, const float* __restrict__ Whh,
    const float* __restrict__ Wm,
    unsigned short* __restrict__ Wihb, unsigned short* __restrict__ Whhb,
    unsigned short* __restrict__ Wmb)
{
    int i = blockIdx.x * 256 + threadIdx.x;
    if (i < 3 * H * H) {
        Wihb[i] = f2bf(Wih[i]);
        Whhb[i] = f2bf(Whh[i]);
    }
    if (i < H * H) Wmb[i] = f2bf(Wm[i]);
}

// ---------------------------------------------------------------------------
// CSR build step 1: degree histogram over dst.
// ---------------------------------------------------------------------------
__global__ __launch_bounds__(256) void hist_kernel(
    const int* __restrict__ eidx, int* __restrict__ deg, int E)
{
    int e = blockIdx.x * 256 + threadIdx.x;
    if (e < E) atomicAdd(&deg[eidx[E + e]], 1);
}

// ---------------------------------------------------------------------------
// CSR build step 2: single-block exclusive scan (N ~ 50k). Writes off[0..N]
// and pos[0..N-1] (= off copy used as fill cursors).
// ---------------------------------------------------------------------------
__global__ __launch_bounds__(1024) void scan_kernel(
    const int* __restrict__ deg, int* __restrict__ off, int* __restrict__ pos, int N)
{
    __shared__ int part[1024];
    int t = threadIdx.x;
    int chunk = (N + 1023) >> 10;
    int s = t * chunk;
    int e = s + chunk < N ? s + chunk : N;
    int sum = 0;
    for (int i = s; i < e; ++i) sum += deg[i];
    part[t] = sum;
    __syncthreads();
    for (int d = 1; d < 1024; d <<= 1) {
        int v = (t >= d) ? part[t - d] : 0;
        __syncthreads();
        part[t] += v;
        __syncthreads();
    }
    int base = (t == 0) ? 0 : part[t - 1];
    for (int i = s; i < e; ++i) {
        off[i] = base;
        pos[i] = base;
        base += deg[i];
    }
    if (t == 1023) off[N] = part[1023];
}

// ---------------------------------------------------------------------------
// CSR build step 3: scatter edge ids into slots; pack src|type into one int.
// ---------------------------------------------------------------------------
__global__ __launch_bounds__(256) void fill_kernel(
    const int* __restrict__ eidx, const int* __restrict__ etype,
    int* __restrict__ pos, int* __restrict__ packed, int E)
{
    int e = blockIdx.x * 256 + threadIdx.x;
    if (e >= E) return;
    int src = eidx[e];
    int dst = eidx[E + e];
    int t = etype[e];
    t = t < 0 ? 0 : (t > 8 ? 8 : t);
    int p = atomicAdd(&pos[dst], 1);
    packed[p] = src | (t << 24);
}

// ---------------------------------------------------------------------------
// Kernel A (MFMA): Xh[n][c] = sum_k h[n][k] * Wm[c][k] + bm[c]
// ---------------------------------------------------------------------------
__global__ __launch_bounds__(256) void xh_mfma_kernel(
    const float* __restrict__ h, const unsigned short* __restrict__ Wmb,
    const float* __restrict__ bm, float* __restrict__ Xh, int N)
{
    __shared__ unsigned short hsb[64 * XS_STRIDE];

    int tid = threadIdx.x;
    int node0 = blockIdx.x * 64;

    for (int c = tid; c < 1024; c += 256) {
        int r = c >> 4;
        int k8 = (c & 15) << 3;
        int n = node0 + r;
        int nc = n < N ? n : N - 1;
        const float4* hp = (const float4*)(h + (size_t)nc * H + k8);
        float4 a = hp[0], b = hp[1];
        short8 v;
        v[0] = (short)f2bf(a.x); v[1] = (short)f2bf(a.y);
        v[2] = (short)f2bf(a.z); v[3] = (short)f2bf(a.w);
        v[4] = (short)f2bf(b.x); v[5] = (short)f2bf(b.y);
        v[6] = (short)f2bf(b.z); v[7] = (short)f2bf(b.w);
        *(short8*)(&hsb[r * XS_STRIDE + k8]) = v;
    }
    __syncthreads();

    int lane = tid & 63;
    int wv = tid >> 6;
    int am = lane & 15;
    int aq = lane >> 4;

    short8 ah[4];
    int arow = wv * 16 + am;
#pragma unroll
    for (int kc = 0; kc < 4; ++kc)
        ah[kc] = *(const short8*)(&hsb[arow * XS_STRIDE + kc * 32 + aq * 8]);

    floatx4 zero = {0.f, 0.f, 0.f, 0.f};
#pragma unroll
    for (int j = 0; j < 8; ++j) {
        floatx4 acc = zero;
#pragma unroll
        for (int kc = 0; kc < 4; ++kc) {
            int ko = kc * 32 + aq * 8;
            short8 b = *(const short8*)(Wmb + (size_t)(j * 16 + am) * H + ko);
            acc = __builtin_amdgcn_mfma_f32_16x16x32_bf16(ah[kc], b, acc, 0, 0, 0);
        }
        int c = j * 16 + am;
        float bias = bm[c];
#pragma unroll
        for (int q = 0; q < 4; ++q) {
            int node = node0 + wv * 16 + aq * 4 + q;
            if (node < N) Xh[(size_t)node * H + c] = acc[q] + bias;
        }
    }
}

// ---------------------------------------------------------------------------
// Kernel B (CSR gather): messages[n] = sum_{e: dst=n} Xh[src_e] + emb[type_e]
// One wave per node; lane covers 2 cols (float2). No atomics. Writes every
// row (zero for isolated nodes) -> no memset of messages needed.
// ---------------------------------------------------------------------------
__global__ __launch_bounds__(256) void gather_kernel(
    const float* __restrict__ Xh, const float* __restrict__ emb,
    const int* __restrict__ off, const int* __restrict__ packed,
    float* __restrict__ messages, int N)
{
    int n = blockIdx.x * 4 + (threadIdx.x >> 6);
    if (n >= N) return;
    int lane = threadIdx.x & 63;
    int b = off[n], e = off[n + 1];
    float ax = 0.f, ay = 0.f;
    for (int i = b; i < e; ++i) {
        int u = packed[i];
        int src = u & 0xffffff;
        int t = u >> 24;
        const float2 xv = *((const float2*)(Xh + (size_t)src * H) + lane);
        const float2 ev = *((const float2*)(emb + (size_t)t * H) + lane);
        ax += xv.x + ev.x;
        ay += xv.y + ev.y;
    }
    float2 o; o.x = ax; o.y = ay;
    *((float2*)(messages + (size_t)n * H) + lane) = o;
}

// ---------------------------------------------------------------------------
// Kernel C (MFMA): fused GRU.
// ---------------------------------------------------------------------------
__global__ __launch_bounds__(256) void gru_mfma_kernel(
    const float* __restrict__ messages, const float* __restrict__ h,
    const unsigned short* __restrict__ Wihb, const unsigned short* __restrict__ Whhb,
    const float* __restrict__ bih, const float* __restrict__ bhh,
    const int* __restrict__ numn, float* __restrict__ out, int N)
{
    __shared__ unsigned short xs[64 * XS_STRIDE];
    __shared__ unsigned short hsb[64 * XS_STRIDE];
    __shared__ float hsf[64 * HS_STRIDE];

    int tid = threadIdx.x;
    int node0 = blockIdx.x * 64;

    for (int c = tid; c < 1024; c += 256) {
        int r = c >> 4;
        int k8 = (c & 15) << 3;
        int n = node0 + r;
        int nc = n < N ? n : N - 1;
        const float4* mp = (const float4*)(messages + (size_t)nc * H + k8);
        float4 m0 = mp[0], m1 = mp[1];
        const float4* hp = (const float4*)(h + (size_t)nc * H + k8);
        float4 h0 = hp[0], h1 = hp[1];
        short8 xv, hv;
        xv[0] = (short)f2bf(m0.x); xv[1] = (short)f2bf(m0.y);
        xv[2] = (short)f2bf(m0.z); xv[3] = (short)f2bf(m0.w);
        xv[4] = (short)f2bf(m1.x); xv[5] = (short)f2bf(m1.y);
        xv[6] = (short)f2bf(m1.z); xv[7] = (short)f2bf(m1.w);
        hv[0] = (short)f2bf(h0.x); hv[1] = (short)f2bf(h0.y);
        hv[2] = (short)f2bf(h0.z); hv[3] = (short)f2bf(h0.w);
        hv[4] = (short)f2bf(h1.x); hv[5] = (short)f2bf(h1.y);
        hv[6] = (short)f2bf(h1.z); hv[7] = (short)f2bf(h1.w);
        *(short8*)(&xs[r * XS_STRIDE + k8]) = xv;
        *(short8*)(&hsb[r * XS_STRIDE + k8]) = hv;
        *(float4*)(&hsf[r * HS_STRIDE + k8]) = h0;
        *(float4*)(&hsf[r * HS_STRIDE + k8 + 4]) = h1;
    }
    __syncthreads();

    int lane = tid & 63;
    int wv = tid >> 6;
    int am = lane & 15;
    int aq = lane >> 4;

    short8 ax[4], ahf[4];
    int arow = wv * 16 + am;
#pragma unroll
    for (int kc = 0; kc < 4; ++kc) {
        ax[kc]  = *(const short8*)(&xs[arow * XS_STRIDE + kc * 32 + aq * 8]);
        ahf[kc] = *(const short8*)(&hsb[arow * XS_STRIDE + kc * 32 + aq * 8]);
    }

    int num_nodes = numn[0];
    floatx4 zero = {0.f, 0.f, 0.f, 0.f};

#pragma unroll
    for (int j = 0; j < 8; ++j) {
        floatx4 aIr = zero, aHr = zero, aIz = zero, aHz = zero, aIn = zero, aHn = zero;
        size_t row_r = (size_t)(j * 16 + am) * H;
        size_t row_z = (size_t)(128 + j * 16 + am) * H;
        size_t row_n = (size_t)(256 + j * 16 + am) * H;
#pragma unroll
        for (int kc = 0; kc < 4; ++kc) {
            int ko = kc * 32 + aq * 8;
            short8 bir = *(const short8*)(Wihb + row_r + ko);
            short8 bhr = *(const short8*)(Whhb + row_r + ko);
            short8 biz = *(const short8*)(Wihb + row_z + ko);
            short8 bhz = *(const short8*)(Whhb + row_z + ko);
            short8 bin = *(const short8*)(Wihb + row_n + ko);
            short8 bhn = *(const short8*)(Whhb + row_n + ko);
            aIr = __builtin_amdgcn_mfma_f32_16x16x32_bf16(ax[kc],  bir, aIr, 0, 0, 0);
            aHr = __builtin_amdgcn_mfma_f32_16x16x32_bf16(ahf[kc], bhr, aHr, 0, 0, 0);
            aIz = __builtin_amdgcn_mfma_f32_16x16x32_bf16(ax[kc],  biz, aIz, 0, 0, 0);
            aHz = __builtin_amdgcn_mfma_f32_16x16x32_bf16(ahf[kc], bhz, aHz, 0, 0, 0);
            aIn = __builtin_amdgcn_mfma_f32_16x16x32_bf16(ax[kc],  bin, aIn, 0, 0, 0);
            aHn = __builtin_amdgcn_mfma_f32_16x16x32_bf16(ahf[kc], bhn, aHn, 0, 0, 0);
        }
        int c = j * 16 + am;
        float b_ir = bih[c],       b_hr = bhh[c];
        float b_iz = bih[128 + c], b_hz = bhh[128 + c];
        float b_in = bih[256 + c], b_hn = bhh[256 + c];
#pragma unroll
        for (int q = 0; q < 4; ++q) {
            int m = aq * 4 + q;
            int node = node0 + wv * 16 + m;
            if (node < N) {
                float r  = sigmoid_f(aIr[q] + b_ir + aHr[q] + b_hr);
                float z  = sigmoid_f(aIz[q] + b_iz + aHz[q] + b_hz);
                float nv = tanh_f((aIn[q] + b_in) + r * (aHn[q] + b_hn));
                float hv = hsf[(wv * 16 + m) * HS_STRIDE + c];
                float o  = (1.0f - z) * nv + z * hv;
                out[(size_t)node * H + c] = (node < num_nodes) ? o : 0.0f;
            }
        }
    }
}

extern "C" void kernel_launch(void* const* d_in, const int* in_sizes, int n_in,
                              void* d_out, int out_size, void* d_ws, size_t ws_size,
                              hipStream_t stream) {
    const float* h    = (const float*)d_in[0];
    const int*  eidx  = (const int*)d_in[1];
    const int*  etype = (const int*)d_in[2];
    const int*  numn  = (const int*)d_in[3];
    const float* Wm   = (const float*)d_in[4];
    const float* bm   = (const float*)d_in[5];
    const float* emb  = (const float*)d_in[6];
    const float* Wih  = (const float*)d_in[7];
    const float* Whh  = (const float*)d_in[8];
    const float* bih  = (const float*)d_in[9];
    const float* bhh  = (const float*)d_in[10];

    int N = in_sizes[0] / H;
    int E = in_sizes[2];

    // ws layout (all 4B-aligned):
    float* messages = (float*)d_ws;                              // N*H f32
    unsigned short* Wihb = (unsigned short*)(messages + (size_t)N * H);
    unsigned short* Whhb = Wihb + 3 * H * H;
    unsigned short* Wmb  = Whhb + 3 * H * H;
    int* deg    = (int*)(Wmb + H * H);                           // N
    int* pos    = deg + N;                                       // N
    int* off    = pos + N;                                       // N+1
    int* packed = off + (N + 1);                                 // E
    float* Xh   = (float*)d_out;                                 // scratch in d_out

    hipMemsetAsync(deg, 0, (size_t)N * sizeof(int), stream);

    convert_w_kernel<<<(3 * H * H + 255) / 256, 256, 0, stream>>>(
        Wih, Whh, Wm, Wihb, Whhb, Wmb);
    hist_kernel<<<(E + 255) / 256, 256, 0, stream>>>(eidx, deg, E);
    scan_kernel<<<1, 1024, 0, stream>>>(deg, off, pos, N);
    fill_kernel<<<(E + 255) / 256, 256, 0, stream>>>(eidx, etype, pos, packed, E);

    int nblk = (N + 63) / 64;
    xh_mfma_kernel<<<nblk, 256, 0, stream>>>(h, Wmb, bm, Xh, N);
    gather_kernel<<<(N + 3) / 4, 256, 0, stream>>>(Xh, emb, off, packed, messages, N);
    gru_mfma_kernel<<<nblk, 256, 0, stream>>>(messages, h, Wihb, Whhb, bih, bhh,
                                              numn, (float*)d_out, N);
}

// Round 6
// 362.376 us; speedup vs baseline: 5.6654x; 1.2698x over previous
//
#include <hip/hip_runtime.h>
#include <math.h>

#define H 128
typedef unsigned int u32;
typedef __attribute__((ext_vector_type(8))) short short8;
typedef __attribute__((ext_vector_type(4))) float floatx4;

#define XS_STRIDE 136   // bf16 elems per padded row (128 + 8)
#define HS_STRIDE 132   // f32 elems per padded row (128 + 4), keeps 16B alignment

#define SCAN_B 64
#define SCAN_T 256

__device__ __forceinline__ float sigmoid_f(float x) {
    return 1.0f / (1.0f + __expf(-x));
}
__device__ __forceinline__ float tanh_f(float x) {
    float t = __expf(-2.0f * fabsf(x));
    float r = (1.0f - t) / (1.0f + t);
    return copysignf(r, x);
}
// f32 -> bf16 bits, round-to-nearest-even (finite inputs)
__device__ __forceinline__ unsigned short f2bf(float x) {
    u32 u = __float_as_uint(x);
    return (unsigned short)((u + 0x7fffu + ((u >> 16) & 1u)) >> 16);
}

// ---------------------------------------------------------------------------
// Convert the three weight matrices to bf16 once per call (into ws).
// ---------------------------------------------------------------------------
__global__ __launch_bounds__(256) void convert_w_kernel(
    const float* __restrict__ Wih, const float* __restrict__ Whh,
    const float* __restrict__ Wm,
    unsigned short* __restrict__ Wihb, unsigned short* __restrict__ Whhb,
    unsigned short* __restrict__ Wmb)
{
    int i = blockIdx.x * 256 + threadIdx.x;
    if (i < 3 * H * H) {
        Wihb[i] = f2bf(Wih[i]);
        Whhb[i] = f2bf(Whh[i]);
    }
    if (i < H * H) Wmb[i] = f2bf(Wm[i]);
}

// ---------------------------------------------------------------------------
// CSR build step 1: degree histogram over dst.
// ---------------------------------------------------------------------------
__global__ __launch_bounds__(256) void hist_kernel(
    const int* __restrict__ eidx, int* __restrict__ deg, int E)
{
    int e = blockIdx.x * 256 + threadIdx.x;
    if (e < E) atomicAdd(&deg[eidx[E + e]], 1);
}

// ---------------------------------------------------------------------------
// CSR build step 2a: per-thread chunk sums + per-block totals (parallel).
// ---------------------------------------------------------------------------
__global__ __launch_bounds__(SCAN_T) void scan_part_kernel(
    const int* __restrict__ deg, int* __restrict__ tsum,
    int* __restrict__ bsum, int N, int ipt)
{
    __shared__ int red[SCAN_T];
    int t = threadIdx.x;
    int g = blockIdx.x * SCAN_T + t;
    int s = g * ipt;
    int e = s + ipt < N ? s + ipt : N;
    int sum = 0;
    for (int i = s; i < e; ++i) sum += deg[i];
    tsum[g] = sum;
    red[t] = sum;
    __syncthreads();
    for (int d = SCAN_T / 2; d > 0; d >>= 1) {
        if (t < d) red[t] += red[t + d];
        __syncthreads();
    }
    if (t == 0) bsum[blockIdx.x] = red[0];
}

// ---------------------------------------------------------------------------
// CSR build step 2b: exclusive scan of the 64 block totals (tiny).
// ---------------------------------------------------------------------------
__global__ __launch_bounds__(64) void scan_mid_kernel(
    int* __restrict__ bsum, int* __restrict__ off, int N)
{
    if (threadIdx.x == 0) {
        int acc = 0;
        for (int b = 0; b < SCAN_B; ++b) { int v = bsum[b]; bsum[b] = acc; acc += v; }
        off[N] = acc;
    }
}

// ---------------------------------------------------------------------------
// CSR build step 2c: block-level scan of thread sums + write off/pos.
// ---------------------------------------------------------------------------
__global__ __launch_bounds__(SCAN_T) void scan_final_kernel(
    const int* __restrict__ deg, const int* __restrict__ tsum,
    const int* __restrict__ bsum, int* __restrict__ off,
    int* __restrict__ pos, int N, int ipt)
{
    __shared__ int part[SCAN_T];
    int t = threadIdx.x;
    int g = blockIdx.x * SCAN_T + t;
    part[t] = tsum[g];
    __syncthreads();
    for (int d = 1; d < SCAN_T; d <<= 1) {
        int v = (t >= d) ? part[t - d] : 0;
        __syncthreads();
        part[t] += v;
        __syncthreads();
    }
    int base = bsum[blockIdx.x] + ((t == 0) ? 0 : part[t - 1]);
    int s = g * ipt;
    int e = s + ipt < N ? s + ipt : N;
    for (int i = s; i < e; ++i) {
        off[i] = base;
        pos[i] = base;
        base += deg[i];
    }
}

// ---------------------------------------------------------------------------
// CSR build step 3: scatter edge ids into slots; pack src|type into one int.
// ---------------------------------------------------------------------------
__global__ __launch_bounds__(256) void fill_kernel(
    const int* __restrict__ eidx, const int* __restrict__ etype,
    int* __restrict__ pos, int* __restrict__ packed, int E)
{
    int e = blockIdx.x * 256 + threadIdx.x;
    if (e >= E) return;
    int src = eidx[e];
    int dst = eidx[E + e];
    int t = etype[e];
    t = t < 0 ? 0 : (t > 8 ? 8 : t);
    int p = atomicAdd(&pos[dst], 1);
    packed[p] = src | (t << 24);
}

// ---------------------------------------------------------------------------
// Kernel A (MFMA): Xh[n][c] = sum_k h[n][k] * Wm[c][k] + bm[c]
// ---------------------------------------------------------------------------
__global__ __launch_bounds__(256) void xh_mfma_kernel(
    const float* __restrict__ h, const unsigned short* __restrict__ Wmb,
    const float* __restrict__ bm, float* __restrict__ Xh, int N)
{
    __shared__ unsigned short hsb[64 * XS_STRIDE];

    int tid = threadIdx.x;
    int node0 = blockIdx.x * 64;

    for (int c = tid; c < 1024; c += 256) {
        int r = c >> 4;
        int k8 = (c & 15) << 3;
        int n = node0 + r;
        int nc = n < N ? n : N - 1;
        const float4* hp = (const float4*)(h + (size_t)nc * H + k8);
        float4 a = hp[0], b = hp[1];
        short8 v;
        v[0] = (short)f2bf(a.x); v[1] = (short)f2bf(a.y);
        v[2] = (short)f2bf(a.z); v[3] = (short)f2bf(a.w);
        v[4] = (short)f2bf(b.x); v[5] = (short)f2bf(b.y);
        v[6] = (short)f2bf(b.z); v[7] = (short)f2bf(b.w);
        *(short8*)(&hsb[r * XS_STRIDE + k8]) = v;
    }
    __syncthreads();

    int lane = tid & 63;
    int wv = tid >> 6;
    int am = lane & 15;
    int aq = lane >> 4;

    short8 ah[4];
    int arow = wv * 16 + am;
#pragma unroll
    for (int kc = 0; kc < 4; ++kc)
        ah[kc] = *(const short8*)(&hsb[arow * XS_STRIDE + kc * 32 + aq * 8]);

    floatx4 zero = {0.f, 0.f, 0.f, 0.f};
#pragma unroll
    for (int j = 0; j < 8; ++j) {
        floatx4 acc = zero;
#pragma unroll
        for (int kc = 0; kc < 4; ++kc) {
            int ko = kc * 32 + aq * 8;
            short8 b = *(const short8*)(Wmb + (size_t)(j * 16 + am) * H + ko);
            acc = __builtin_amdgcn_mfma_f32_16x16x32_bf16(ah[kc], b, acc, 0, 0, 0);
        }
        int c = j * 16 + am;
        float bias = bm[c];
#pragma unroll
        for (int q = 0; q < 4; ++q) {
            int node = node0 + wv * 16 + aq * 4 + q;
            if (node < N) Xh[(size_t)node * H + c] = acc[q] + bias;
        }
    }
}

// ---------------------------------------------------------------------------
// Kernel B (CSR gather): messages[n] = sum_{e: dst=n} Xh[src_e] + emb[type_e]
// One wave per node; lane covers 2 cols (float2). No atomics.
// ---------------------------------------------------------------------------
__global__ __launch_bounds__(256) void gather_kernel(
    const float* __restrict__ Xh, const float* __restrict__ emb,
    const int* __restrict__ off, const int* __restrict__ packed,
    float* __restrict__ messages, int N)
{
    int n = blockIdx.x * 4 + (threadIdx.x >> 6);
    if (n >= N) return;
    int lane = threadIdx.x & 63;
    int b = off[n], e = off[n + 1];
    float ax = 0.f, ay = 0.f;
    for (int i = b; i < e; ++i) {
        int u = packed[i];
        int src = u & 0xffffff;
        int t = u >> 24;
        const float2 xv = *((const float2*)(Xh + (size_t)src * H) + lane);
        const float2 ev = *((const float2*)(emb + (size_t)t * H) + lane);
        ax += xv.x + ev.x;
        ay += xv.y + ev.y;
    }
    float2 o; o.x = ax; o.y = ay;
    *((float2*)(messages + (size_t)n * H) + lane) = o;
}

// ---------------------------------------------------------------------------
// Kernel C (MFMA): fused GRU.
// ---------------------------------------------------------------------------
__global__ __launch_bounds__(256) void gru_mfma_kernel(
    const float* __restrict__ messages, const float* __restrict__ h,
    const unsigned short* __restrict__ Wihb, const unsigned short* __restrict__ Whhb,
    const float* __restrict__ bih, const float* __restrict__ bhh,
    const int* __restrict__ numn, float* __restrict__ out, int N)
{
    __shared__ unsigned short xs[64 * XS_STRIDE];
    __shared__ unsigned short hsb[64 * XS_STRIDE];
    __shared__ float hsf[64 * HS_STRIDE];

    int tid = threadIdx.x;
    int node0 = blockIdx.x * 64;

    for (int c = tid; c < 1024; c += 256) {
        int r = c >> 4;
        int k8 = (c & 15) << 3;
        int n = node0 + r;
        int nc = n < N ? n : N - 1;
        const float4* mp = (const float4*)(messages + (size_t)nc * H + k8);
        float4 m0 = mp[0], m1 = mp[1];
        const float4* hp = (const float4*)(h + (size_t)nc * H + k8);
        float4 h0 = hp[0], h1 = hp[1];
        short8 xv, hv;
        xv[0] = (short)f2bf(m0.x); xv[1] = (short)f2bf(m0.y);
        xv[2] = (short)f2bf(m0.z); xv[3] = (short)f2bf(m0.w);
        xv[4] = (short)f2bf(m1.x); xv[5] = (short)f2bf(m1.y);
        xv[6] = (short)f2bf(m1.z); xv[7] = (short)f2bf(m1.w);
        hv[0] = (short)f2bf(h0.x); hv[1] = (short)f2bf(h0.y);
        hv[2] = (short)f2bf(h0.z); hv[3] = (short)f2bf(h0.w);
        hv[4] = (short)f2bf(h1.x); hv[5] = (short)f2bf(h1.y);
        hv[6] = (short)f2bf(h1.z); hv[7] = (short)f2bf(h1.w);
        *(short8*)(&xs[r * XS_STRIDE + k8]) = xv;
        *(short8*)(&hsb[r * XS_STRIDE + k8]) = hv;
        *(float4*)(&hsf[r * HS_STRIDE + k8]) = h0;
        *(float4*)(&hsf[r * HS_STRIDE + k8 + 4]) = h1;
    }
    __syncthreads();

    int lane = tid & 63;
    int wv = tid >> 6;
    int am = lane & 15;
    int aq = lane >> 4;

    short8 ax[4], ahf[4];
    int arow = wv * 16 + am;
#pragma unroll
    for (int kc = 0; kc < 4; ++kc) {
        ax[kc]  = *(const short8*)(&xs[arow * XS_STRIDE + kc * 32 + aq * 8]);
        ahf[kc] = *(const short8*)(&hsb[arow * XS_STRIDE + kc * 32 + aq * 8]);
    }

    int num_nodes = numn[0];
    floatx4 zero = {0.f, 0.f, 0.f, 0.f};

#pragma unroll
    for (int j = 0; j < 8; ++j) {
        floatx4 aIr = zero, aHr = zero, aIz = zero, aHz = zero, aIn = zero, aHn = zero;
        size_t row_r = (size_t)(j * 16 + am) * H;
        size_t row_z = (size_t)(128 + j * 16 + am) * H;
        size_t row_n = (size_t)(256 + j * 16 + am) * H;
#pragma unroll
        for (int kc = 0; kc < 4; ++kc) {
            int ko = kc * 32 + aq * 8;
            short8 bir = *(const short8*)(Wihb + row_r + ko);
            short8 bhr = *(const short8*)(Whhb + row_r + ko);
            short8 biz = *(const short8*)(Wihb + row_z + ko);
            short8 bhz = *(const short8*)(Whhb + row_z + ko);
            short8 bin = *(const short8*)(Wihb + row_n + ko);
            short8 bhn = *(const short8*)(Whhb + row_n + ko);
            aIr = __builtin_amdgcn_mfma_f32_16x16x32_bf16(ax[kc],  bir, aIr, 0, 0, 0);
            aHr = __builtin_amdgcn_mfma_f32_16x16x32_bf16(ahf[kc], bhr, aHr, 0, 0, 0);
            aIz = __builtin_amdgcn_mfma_f32_16x16x32_bf16(ax[kc],  biz, aIz, 0, 0, 0);
            aHz = __builtin_amdgcn_mfma_f32_16x16x32_bf16(ahf[kc], bhz, aHz, 0, 0, 0);
            aIn = __builtin_amdgcn_mfma_f32_16x16x32_bf16(ax[kc],  bin, aIn, 0, 0, 0);
            aHn = __builtin_amdgcn_mfma_f32_16x16x32_bf16(ahf[kc], bhn, aHn, 0, 0, 0);
        }
        int c = j * 16 + am;
        float b_ir = bih[c],       b_hr = bhh[c];
        float b_iz = bih[128 + c], b_hz = bhh[128 + c];
        float b_in = bih[256 + c], b_hn = bhh[256 + c];
#pragma unroll
        for (int q = 0; q < 4; ++q) {
            int m = aq * 4 + q;
            int node = node0 + wv * 16 + m;
            if (node < N) {
                float r  = sigmoid_f(aIr[q] + b_ir + aHr[q] + b_hr);
                float z  = sigmoid_f(aIz[q] + b_iz + aHz[q] + b_hz);
                float nv = tanh_f((aIn[q] + b_in) + r * (aHn[q] + b_hn));
                float hv = hsf[(wv * 16 + m) * HS_STRIDE + c];
                float o  = (1.0f - z) * nv + z * hv;
                out[(size_t)node * H + c] = (node < num_nodes) ? o : 0.0f;
            }
        }
    }
}

extern "C" void kernel_launch(void* const* d_in, const int* in_sizes, int n_in,
                              void* d_out, int out_size, void* d_ws, size_t ws_size,
                              hipStream_t stream) {
    const float* h    = (const float*)d_in[0];
    const int*  eidx  = (const int*)d_in[1];
    const int*  etype = (const int*)d_in[2];
    const int*  numn  = (const int*)d_in[3];
    const float* Wm   = (const float*)d_in[4];
    const float* bm   = (const float*)d_in[5];
    const float* emb  = (const float*)d_in[6];
    const float* Wih  = (const float*)d_in[7];
    const float* Whh  = (const float*)d_in[8];
    const float* bih  = (const float*)d_in[9];
    const float* bhh  = (const float*)d_in[10];

    int N = in_sizes[0] / H;
    int E = in_sizes[2];

    // ws layout (all 4B-aligned):
    float* messages = (float*)d_ws;                              // N*H f32
    unsigned short* Wihb = (unsigned short*)(messages + (size_t)N * H);
    unsigned short* Whhb = Wihb + 3 * H * H;
    unsigned short* Wmb  = Whhb + 3 * H * H;
    int* deg    = (int*)(Wmb + H * H);                           // N
    int* pos    = deg + N;                                       // N
    int* off    = pos + N;                                       // N+1
    int* packed = off + (N + 1);                                 // E
    int* tsum   = packed + E;                                    // SCAN_B*SCAN_T
    int* bsum   = tsum + SCAN_B * SCAN_T;                        // SCAN_B
    float* Xh   = (float*)d_out;                                 // scratch in d_out

    hipMemsetAsync(deg, 0, (size_t)N * sizeof(int), stream);

    convert_w_kernel<<<(3 * H * H + 255) / 256, 256, 0, stream>>>(
        Wih, Whh, Wm, Wihb, Whhb, Wmb);
    hist_kernel<<<(E + 255) / 256, 256, 0, stream>>>(eidx, deg, E);

    int ipt = (N + SCAN_B * SCAN_T - 1) / (SCAN_B * SCAN_T);
    scan_part_kernel<<<SCAN_B, SCAN_T, 0, stream>>>(deg, tsum, bsum, N, ipt);
    scan_mid_kernel<<<1, 64, 0, stream>>>(bsum, off, N);
    scan_final_kernel<<<SCAN_B, SCAN_T, 0, stream>>>(deg, tsum, bsum, off, pos, N, ipt);

    fill_kernel<<<(E + 255) / 256, 256, 0, stream>>>(eidx, etype, pos, packed, E);

    int nblk = (N + 63) / 64;
    xh_mfma_kernel<<<nblk, 256, 0, stream>>>(h, Wmb, bm, Xh, N);
    gather_kernel<<<(N + 3) / 4, 256, 0, stream>>>(Xh, emb, off, packed, messages, N);
    gru_mfma_kernel<<<nblk, 256, 0, stream>>>(messages, h, Wihb, Whhb, bih, bhh,
                                              numn, (float*)d_out, N);
}

// Round 7
// 350.062 us; speedup vs baseline: 5.8647x; 1.0352x over previous
//
#include <hip/hip_runtime.h>
#include <math.h>

#define H 128
typedef unsigned int u32;
typedef __attribute__((ext_vector_type(8))) short short8;
typedef __attribute__((ext_vector_type(4))) float floatx4;

#define XS_STRIDE 136   // bf16 elems per padded row (128 + 8)

#define SCAN_B 64
#define SCAN_T 256

__device__ __forceinline__ float sigmoid_f(float x) {
    return 1.0f / (1.0f + __expf(-x));
}
__device__ __forceinline__ float tanh_f(float x) {
    float t = __expf(-2.0f * fabsf(x));
    float r = (1.0f - t) / (1.0f + t);
    return copysignf(r, x);
}
// f32 -> bf16 bits, round-to-nearest-even (finite inputs)
__device__ __forceinline__ unsigned short f2bf(float x) {
    u32 u = __float_as_uint(x);
    return (unsigned short)((u + 0x7fffu + ((u >> 16) & 1u)) >> 16);
}
__device__ __forceinline__ float bf2f(unsigned short s) {
    return __uint_as_float(((u32)s) << 16);
}

// ---------------------------------------------------------------------------
// Convert the three weight matrices to bf16 once per call (into ws).
// ---------------------------------------------------------------------------
__global__ __launch_bounds__(256) void convert_w_kernel(
    const float* __restrict__ Wih, const float* __restrict__ Whh,
    const float* __restrict__ Wm,
    unsigned short* __restrict__ Wihb, unsigned short* __restrict__ Whhb,
    unsigned short* __restrict__ Wmb)
{
    int i = blockIdx.x * 256 + threadIdx.x;
    if (i < 3 * H * H) {
        Wihb[i] = f2bf(Wih[i]);
        Whhb[i] = f2bf(Whh[i]);
    }
    if (i < H * H) Wmb[i] = f2bf(Wm[i]);
}

// ---------------------------------------------------------------------------
// CSR build step 1: degree histogram over dst.
// ---------------------------------------------------------------------------
__global__ __launch_bounds__(256) void hist_kernel(
    const int* __restrict__ eidx, int* __restrict__ deg, int E)
{
    int e = blockIdx.x * 256 + threadIdx.x;
    if (e < E) atomicAdd(&deg[eidx[E + e]], 1);
}

// ---------------------------------------------------------------------------
// CSR build step 2a: per-thread chunk sums + per-block totals (parallel).
// ---------------------------------------------------------------------------
__global__ __launch_bounds__(SCAN_T) void scan_part_kernel(
    const int* __restrict__ deg, int* __restrict__ tsum,
    int* __restrict__ bsum, int N, int ipt)
{
    __shared__ int red[SCAN_T];
    int t = threadIdx.x;
    int g = blockIdx.x * SCAN_T + t;
    int s = g * ipt;
    int e = s + ipt < N ? s + ipt : N;
    int sum = 0;
    for (int i = s; i < e; ++i) sum += deg[i];
    tsum[g] = sum;
    red[t] = sum;
    __syncthreads();
    for (int d = SCAN_T / 2; d > 0; d >>= 1) {
        if (t < d) red[t] += red[t + d];
        __syncthreads();
    }
    if (t == 0) bsum[blockIdx.x] = red[0];
}

// ---------------------------------------------------------------------------
// CSR build step 2b: exclusive scan of the 64 block totals (tiny).
// ---------------------------------------------------------------------------
__global__ __launch_bounds__(64) void scan_mid_kernel(
    int* __restrict__ bsum, int* __restrict__ off, int N)
{
    if (threadIdx.x == 0) {
        int acc = 0;
        for (int b = 0; b < SCAN_B; ++b) { int v = bsum[b]; bsum[b] = acc; acc += v; }
        off[N] = acc;
    }
}

// ---------------------------------------------------------------------------
// CSR build step 2c: block-level scan of thread sums + write off/pos.
// ---------------------------------------------------------------------------
__global__ __launch_bounds__(SCAN_T) void scan_final_kernel(
    const int* __restrict__ deg, const int* __restrict__ tsum,
    const int* __restrict__ bsum, int* __restrict__ off,
    int* __restrict__ pos, int N, int ipt)
{
    __shared__ int part[SCAN_T];
    int t = threadIdx.x;
    int g = blockIdx.x * SCAN_T + t;
    part[t] = tsum[g];
    __syncthreads();
    for (int d = 1; d < SCAN_T; d <<= 1) {
        int v = (t >= d) ? part[t - d] : 0;
        __syncthreads();
        part[t] += v;
        __syncthreads();
    }
    int base = bsum[blockIdx.x] + ((t == 0) ? 0 : part[t - 1]);
    int s = g * ipt;
    int e = s + ipt < N ? s + ipt : N;
    for (int i = s; i < e; ++i) {
        off[i] = base;
        pos[i] = base;
        base += deg[i];
    }
}

// ---------------------------------------------------------------------------
// CSR build step 3: scatter edge ids into slots; pack src|type into one int.
// ---------------------------------------------------------------------------
__global__ __launch_bounds__(256) void fill_kernel(
    const int* __restrict__ eidx, const int* __restrict__ etype,
    int* __restrict__ pos, int* __restrict__ packed, int E)
{
    int e = blockIdx.x * 256 + threadIdx.x;
    if (e >= E) return;
    int src = eidx[e];
    int dst = eidx[E + e];
    int t = etype[e];
    t = t < 0 ? 0 : (t > 8 ? 8 : t);
    int p = atomicAdd(&pos[dst], 1);
    packed[p] = src | (t << 24);
}

// ---------------------------------------------------------------------------
// Kernel A (MFMA): Xh[n][c] = sum_k h[n][k] * Wm[c][k] + bm[c]
// ---------------------------------------------------------------------------
__global__ __launch_bounds__(256) void xh_mfma_kernel(
    const float* __restrict__ h, const unsigned short* __restrict__ Wmb,
    const float* __restrict__ bm, float* __restrict__ Xh, int N)
{
    __shared__ unsigned short hsb[64 * XS_STRIDE];

    int tid = threadIdx.x;
    int node0 = blockIdx.x * 64;

    for (int c = tid; c < 1024; c += 256) {
        int r = c >> 4;
        int k8 = (c & 15) << 3;
        int n = node0 + r;
        int nc = n < N ? n : N - 1;
        const float4* hp = (const float4*)(h + (size_t)nc * H + k8);
        float4 a = hp[0], b = hp[1];
        short8 v;
        v[0] = (short)f2bf(a.x); v[1] = (short)f2bf(a.y);
        v[2] = (short)f2bf(a.z); v[3] = (short)f2bf(a.w);
        v[4] = (short)f2bf(b.x); v[5] = (short)f2bf(b.y);
        v[6] = (short)f2bf(b.z); v[7] = (short)f2bf(b.w);
        *(short8*)(&hsb[r * XS_STRIDE + k8]) = v;
    }
    __syncthreads();

    int lane = tid & 63;
    int wv = tid >> 6;
    int am = lane & 15;
    int aq = lane >> 4;

    short8 ah[4];
    int arow = wv * 16 + am;
#pragma unroll
    for (int kc = 0; kc < 4; ++kc)
        ah[kc] = *(const short8*)(&hsb[arow * XS_STRIDE + kc * 32 + aq * 8]);

    floatx4 zero = {0.f, 0.f, 0.f, 0.f};
#pragma unroll
    for (int j = 0; j < 8; ++j) {
        floatx4 acc = zero;
#pragma unroll
        for (int kc = 0; kc < 4; ++kc) {
            int ko = kc * 32 + aq * 8;
            short8 b = *(const short8*)(Wmb + (size_t)(j * 16 + am) * H + ko);
            acc = __builtin_amdgcn_mfma_f32_16x16x32_bf16(ah[kc], b, acc, 0, 0, 0);
        }
        int c = j * 16 + am;
        float bias = bm[c];
#pragma unroll
        for (int q = 0; q < 4; ++q) {
            int node = node0 + wv * 16 + aq * 4 + q;
            if (node < N) Xh[(size_t)node * H + c] = acc[q] + bias;
        }
    }
}

// ---------------------------------------------------------------------------
// Kernel B (CSR gather): messages[n] = sum_{e: dst=n} Xh[src_e] + emb[type_e]
// One wave per node; lane covers 2 cols. Accumulate f32, emit bf16 (identical
// rounding to what gru staging previously applied).
// ---------------------------------------------------------------------------
__global__ __launch_bounds__(256) void gather_kernel(
    const float* __restrict__ Xh, const float* __restrict__ emb,
    const int* __restrict__ off, const int* __restrict__ packed,
    unsigned short* __restrict__ messages_b, int N)
{
    int n = blockIdx.x * 4 + (threadIdx.x >> 6);
    if (n >= N) return;
    int lane = threadIdx.x & 63;
    int b = off[n], e = off[n + 1];
    float ax = 0.f, ay = 0.f;
    for (int i = b; i < e; ++i) {
        int u = packed[i];
        int src = u & 0xffffff;
        int t = u >> 24;
        const float2 xv = *((const float2*)(Xh + (size_t)src * H) + lane);
        const float2 ev = *((const float2*)(emb + (size_t)t * H) + lane);
        ax += xv.x + ev.x;
        ay += xv.y + ev.y;
    }
    u32 o = (u32)f2bf(ax) | ((u32)f2bf(ay) << 16);
    *((u32*)(messages_b + (size_t)n * H) + lane) = o;
}

// ---------------------------------------------------------------------------
// Kernel C (MFMA): fused GRU. LDS = xs + hsb only (34.8 KB -> 4 blocks/CU).
// Epilogue h comes from hsb (bf16): +<=0.009 abs error, within budget.
// ---------------------------------------------------------------------------
__global__ __launch_bounds__(256) void gru_mfma_kernel(
    const unsigned short* __restrict__ messages_b, const float* __restrict__ h,
    const unsigned short* __restrict__ Wihb, const unsigned short* __restrict__ Whhb,
    const float* __restrict__ bih, const float* __restrict__ bhh,
    const int* __restrict__ numn, float* __restrict__ out, int N)
{
    __shared__ unsigned short xs[64 * XS_STRIDE];
    __shared__ unsigned short hsb[64 * XS_STRIDE];

    int tid = threadIdx.x;
    int node0 = blockIdx.x * 64;

    for (int c = tid; c < 1024; c += 256) {
        int r = c >> 4;
        int k8 = (c & 15) << 3;
        int n = node0 + r;
        int nc = n < N ? n : N - 1;
        // messages: already bf16 — straight 16B copy
        short8 xv = *(const short8*)(messages_b + (size_t)nc * H + k8);
        const float4* hp = (const float4*)(h + (size_t)nc * H + k8);
        float4 h0 = hp[0], h1 = hp[1];
        short8 hv;
        hv[0] = (short)f2bf(h0.x); hv[1] = (short)f2bf(h0.y);
        hv[2] = (short)f2bf(h0.z); hv[3] = (short)f2bf(h0.w);
        hv[4] = (short)f2bf(h1.x); hv[5] = (short)f2bf(h1.y);
        hv[6] = (short)f2bf(h1.z); hv[7] = (short)f2bf(h1.w);
        *(short8*)(&xs[r * XS_STRIDE + k8]) = xv;
        *(short8*)(&hsb[r * XS_STRIDE + k8]) = hv;
    }
    __syncthreads();

    int lane = tid & 63;
    int wv = tid >> 6;
    int am = lane & 15;
    int aq = lane >> 4;

    short8 ax[4], ahf[4];
    int arow = wv * 16 + am;
#pragma unroll
    for (int kc = 0; kc < 4; ++kc) {
        ax[kc]  = *(const short8*)(&xs[arow * XS_STRIDE + kc * 32 + aq * 8]);
        ahf[kc] = *(const short8*)(&hsb[arow * XS_STRIDE + kc * 32 + aq * 8]);
    }

    int num_nodes = numn[0];
    floatx4 zero = {0.f, 0.f, 0.f, 0.f};

#pragma unroll
    for (int j = 0; j < 8; ++j) {
        floatx4 aIr = zero, aHr = zero, aIz = zero, aHz = zero, aIn = zero, aHn = zero;
        size_t row_r = (size_t)(j * 16 + am) * H;
        size_t row_z = (size_t)(128 + j * 16 + am) * H;
        size_t row_n = (size_t)(256 + j * 16 + am) * H;
#pragma unroll
        for (int kc = 0; kc < 4; ++kc) {
            int ko = kc * 32 + aq * 8;
            short8 bir = *(const short8*)(Wihb + row_r + ko);
            short8 bhr = *(const short8*)(Whhb + row_r + ko);
            short8 biz = *(const short8*)(Wihb + row_z + ko);
            short8 bhz = *(const short8*)(Whhb + row_z + ko);
            short8 bin = *(const short8*)(Wihb + row_n + ko);
            short8 bhn = *(const short8*)(Whhb + row_n + ko);
            aIr = __builtin_amdgcn_mfma_f32_16x16x32_bf16(ax[kc],  bir, aIr, 0, 0, 0);
            aHr = __builtin_amdgcn_mfma_f32_16x16x32_bf16(ahf[kc], bhr, aHr, 0, 0, 0);
            aIz = __builtin_amdgcn_mfma_f32_16x16x32_bf16(ax[kc],  biz, aIz, 0, 0, 0);
            aHz = __builtin_amdgcn_mfma_f32_16x16x32_bf16(ahf[kc], bhz, aHz, 0, 0, 0);
            aIn = __builtin_amdgcn_mfma_f32_16x16x32_bf16(ax[kc],  bin, aIn, 0, 0, 0);
            aHn = __builtin_amdgcn_mfma_f32_16x16x32_bf16(ahf[kc], bhn, aHn, 0, 0, 0);
        }
        int c = j * 16 + am;
        float b_ir = bih[c],       b_hr = bhh[c];
        float b_iz = bih[128 + c], b_hz = bhh[128 + c];
        float b_in = bih[256 + c], b_hn = bhh[256 + c];
#pragma unroll
        for (int q = 0; q < 4; ++q) {
            int m = aq * 4 + q;
            int node = node0 + wv * 16 + m;
            if (node < N) {
                float r  = sigmoid_f(aIr[q] + b_ir + aHr[q] + b_hr);
                float z  = sigmoid_f(aIz[q] + b_iz + aHz[q] + b_hz);
                float nv = tanh_f((aIn[q] + b_in) + r * (aHn[q] + b_hn));
                float hv = bf2f(hsb[(wv * 16 + m) * XS_STRIDE + c]);
                float o  = (1.0f - z) * nv + z * hv;
                out[(size_t)node * H + c] = (node < num_nodes) ? o : 0.0f;
            }
        }
    }
}

extern "C" void kernel_launch(void* const* d_in, const int* in_sizes, int n_in,
                              void* d_out, int out_size, void* d_ws, size_t ws_size,
                              hipStream_t stream) {
    const float* h    = (const float*)d_in[0];
    const int*  eidx  = (const int*)d_in[1];
    const int*  etype = (const int*)d_in[2];
    const int*  numn  = (const int*)d_in[3];
    const float* Wm   = (const float*)d_in[4];
    const float* bm   = (const float*)d_in[5];
    const float* emb  = (const float*)d_in[6];
    const float* Wih  = (const float*)d_in[7];
    const float* Whh  = (const float*)d_in[8];
    const float* bih  = (const float*)d_in[9];
    const float* bhh  = (const float*)d_in[10];

    int N = in_sizes[0] / H;
    int E = in_sizes[2];

    // ws layout (messages now bf16):
    unsigned short* messages_b = (unsigned short*)d_ws;          // N*H bf16
    unsigned short* Wihb = messages_b + (size_t)N * H;           // 3*H*H
    unsigned short* Whhb = Wihb + 3 * H * H;                     // 3*H*H
    unsigned short* Wmb  = Whhb + 3 * H * H;                     // H*H
    int* deg    = (int*)(Wmb + H * H);                           // N
    int* pos    = deg + N;                                       // N
    int* off    = pos + N;                                       // N+1
    int* packed = off + (N + 1);                                 // E
    int* tsum   = packed + E;                                    // SCAN_B*SCAN_T
    int* bsum   = tsum + SCAN_B * SCAN_T;                        // SCAN_B
    float* Xh   = (float*)d_out;                                 // scratch in d_out

    hipMemsetAsync(deg, 0, (size_t)N * sizeof(int), stream);

    convert_w_kernel<<<(3 * H * H + 255) / 256, 256, 0, stream>>>(
        Wih, Whh, Wm, Wihb, Whhb, Wmb);
    hist_kernel<<<(E + 255) / 256, 256, 0, stream>>>(eidx, deg, E);

    int ipt = (N + SCAN_B * SCAN_T - 1) / (SCAN_B * SCAN_T);
    scan_part_kernel<<<SCAN_B, SCAN_T, 0, stream>>>(deg, tsum, bsum, N, ipt);
    scan_mid_kernel<<<1, 64, 0, stream>>>(bsum, off, N);
    scan_final_kernel<<<SCAN_B, SCAN_T, 0, stream>>>(deg, tsum, bsum, off, pos, N, ipt);

    fill_kernel<<<(E + 255) / 256, 256, 0, stream>>>(eidx, etype, pos, packed, E);

    int nblk = (N + 63) / 64;
    xh_mfma_kernel<<<nblk, 256, 0, stream>>>(h, Wmb, bm, Xh, N);
    gather_kernel<<<(N + 3) / 4, 256, 0, stream>>>(Xh, emb, off, packed, messages_b, N);
    gru_mfma_kernel<<<nblk, 256, 0, stream>>>(messages_b, h, Wihb, Whhb, bih, bhh,
                                              numn, (float*)d_out, N);
}

// Round 8
// 285.640 us; speedup vs baseline: 7.1874x; 1.2255x over previous
//
#include <hip/hip_runtime.h>
#include <math.h>

#define H 128
typedef unsigned int u32;
typedef __attribute__((ext_vector_type(8))) short short8;
typedef __attribute__((ext_vector_type(4))) float floatx4;

#define XS_STRIDE 136   // bf16 elems per padded row (128 + 8)

#define SCAN_B 64
#define SCAN_T 256

__device__ __forceinline__ float sigmoid_f(float x) {
    return 1.0f / (1.0f + __expf(-x));
}
__device__ __forceinline__ float tanh_f(float x) {
    float t = __expf(-2.0f * fabsf(x));
    float r = (1.0f - t) / (1.0f + t);
    return copysignf(r, x);
}
// f32 -> bf16 bits, round-to-nearest-even (finite inputs)
__device__ __forceinline__ unsigned short f2bf(float x) {
    u32 u = __float_as_uint(x);
    return (unsigned short)((u + 0x7fffu + ((u >> 16) & 1u)) >> 16);
}
__device__ __forceinline__ float bf2f(unsigned short s) {
    return __uint_as_float(((u32)s) << 16);
}

// ---------------------------------------------------------------------------
// Convert + SWIZZLE weights into MFMA B-fragment order (bf16):
// out[((jr*4+kc)*64 + l)*8 + i] = W[(jr*16 + (l&15))*H + kc*32 + (l>>4)*8 + i]
// => in-kernel, lane l's fragment for (jr,kc) is a coalesced load at
//    base + ((jr*4+kc)*64 + l)*8.
// Wih/Whh: R=384 -> 6144 chunk-lanes. Wm: R=128 -> 2048 chunk-lanes.
// ---------------------------------------------------------------------------
__global__ __launch_bounds__(256) void convert_w_kernel(
    const float* __restrict__ Wih, const float* __restrict__ Whh,
    const float* __restrict__ Wm,
    unsigned short* __restrict__ Wihs, unsigned short* __restrict__ Whhs,
    unsigned short* __restrict__ Wms)
{
    int idx = blockIdx.x * 256 + threadIdx.x;   // chunk-lane id
    if (idx >= 6144) return;
    int l  = idx & 63;
    int kc = (idx >> 6) & 3;
    int jr = idx >> 8;
    int m = l & 15, q = l >> 4;
    size_t srco = (size_t)(jr * 16 + m) * H + kc * 32 + q * 8;

    {
        const float4* s0 = (const float4*)(Wih + srco);
        float4 a = s0[0], b = s0[1];
        short8 v;
        v[0] = (short)f2bf(a.x); v[1] = (short)f2bf(a.y);
        v[2] = (short)f2bf(a.z); v[3] = (short)f2bf(a.w);
        v[4] = (short)f2bf(b.x); v[5] = (short)f2bf(b.y);
        v[6] = (short)f2bf(b.z); v[7] = (short)f2bf(b.w);
        *(short8*)(Wihs + (size_t)idx * 8) = v;
    }
    {
        const float4* s0 = (const float4*)(Whh + srco);
        float4 a = s0[0], b = s0[1];
        short8 v;
        v[0] = (short)f2bf(a.x); v[1] = (short)f2bf(a.y);
        v[2] = (short)f2bf(a.z); v[3] = (short)f2bf(a.w);
        v[4] = (short)f2bf(b.x); v[5] = (short)f2bf(b.y);
        v[6] = (short)f2bf(b.z); v[7] = (short)f2bf(b.w);
        *(short8*)(Whhs + (size_t)idx * 8) = v;
    }
    if (idx < 2048) {
        const float4* s0 = (const float4*)(Wm + srco);
        float4 a = s0[0], b = s0[1];
        short8 v;
        v[0] = (short)f2bf(a.x); v[1] = (short)f2bf(a.y);
        v[2] = (short)f2bf(a.z); v[3] = (short)f2bf(a.w);
        v[4] = (short)f2bf(b.x); v[5] = (short)f2bf(b.y);
        v[6] = (short)f2bf(b.z); v[7] = (short)f2bf(b.w);
        *(short8*)(Wms + (size_t)idx * 8) = v;
    }
}

// ---------------------------------------------------------------------------
// CSR build step 1: degree histogram over dst.
// ---------------------------------------------------------------------------
__global__ __launch_bounds__(256) void hist_kernel(
    const int* __restrict__ eidx, int* __restrict__ deg, int E)
{
    int e = blockIdx.x * 256 + threadIdx.x;
    if (e < E) atomicAdd(&deg[eidx[E + e]], 1);
}

// ---------------------------------------------------------------------------
// CSR build step 2a: per-thread chunk sums + per-block totals (parallel).
// ---------------------------------------------------------------------------
__global__ __launch_bounds__(SCAN_T) void scan_part_kernel(
    const int* __restrict__ deg, int* __restrict__ tsum,
    int* __restrict__ bsum, int N, int ipt)
{
    __shared__ int red[SCAN_T];
    int t = threadIdx.x;
    int g = blockIdx.x * SCAN_T + t;
    int s = g * ipt;
    int e = s + ipt < N ? s + ipt : N;
    int sum = 0;
    for (int i = s; i < e; ++i) sum += deg[i];
    tsum[g] = sum;
    red[t] = sum;
    __syncthreads();
    for (int d = SCAN_T / 2; d > 0; d >>= 1) {
        if (t < d) red[t] += red[t + d];
        __syncthreads();
    }
    if (t == 0) bsum[blockIdx.x] = red[0];
}

// ---------------------------------------------------------------------------
// CSR build step 2b: exclusive scan of the 64 block totals (tiny).
// ---------------------------------------------------------------------------
__global__ __launch_bounds__(64) void scan_mid_kernel(
    int* __restrict__ bsum, int* __restrict__ off, int N)
{
    if (threadIdx.x == 0) {
        int acc = 0;
        for (int b = 0; b < SCAN_B; ++b) { int v = bsum[b]; bsum[b] = acc; acc += v; }
        off[N] = acc;
    }
}

// ---------------------------------------------------------------------------
// CSR build step 2c: block-level scan of thread sums + write off/pos.
// ---------------------------------------------------------------------------
__global__ __launch_bounds__(SCAN_T) void scan_final_kernel(
    const int* __restrict__ deg, const int* __restrict__ tsum,
    const int* __restrict__ bsum, int* __restrict__ off,
    int* __restrict__ pos, int N, int ipt)
{
    __shared__ int part[SCAN_T];
    int t = threadIdx.x;
    int g = blockIdx.x * SCAN_T + t;
    part[t] = tsum[g];
    __syncthreads();
    for (int d = 1; d < SCAN_T; d <<= 1) {
        int v = (t >= d) ? part[t - d] : 0;
        __syncthreads();
        part[t] += v;
        __syncthreads();
    }
    int base = bsum[blockIdx.x] + ((t == 0) ? 0 : part[t - 1]);
    int s = g * ipt;
    int e = s + ipt < N ? s + ipt : N;
    for (int i = s; i < e; ++i) {
        off[i] = base;
        pos[i] = base;
        base += deg[i];
    }
}

// ---------------------------------------------------------------------------
// CSR build step 3: scatter edge ids into slots; pack src|type into one int.
// ---------------------------------------------------------------------------
__global__ __launch_bounds__(256) void fill_kernel(
    const int* __restrict__ eidx, const int* __restrict__ etype,
    int* __restrict__ pos, int* __restrict__ packed, int E)
{
    int e = blockIdx.x * 256 + threadIdx.x;
    if (e >= E) return;
    int src = eidx[e];
    int dst = eidx[E + e];
    int t = etype[e];
    t = t < 0 ? 0 : (t > 8 ? 8 : t);
    int p = atomicAdd(&pos[dst], 1);
    packed[p] = src | (t << 24);
}

// ---------------------------------------------------------------------------
// Kernel A (MFMA): Xh[n][c] = sum_k h[n][k] * Wm[c][k] + bm[c]
// B loads now coalesced via swizzled Wms.
// ---------------------------------------------------------------------------
__global__ __launch_bounds__(256) void xh_mfma_kernel(
    const float* __restrict__ h, const unsigned short* __restrict__ Wms,
    const float* __restrict__ bm, float* __restrict__ Xh, int N)
{
    __shared__ unsigned short hsb[64 * XS_STRIDE];

    int tid = threadIdx.x;
    int node0 = blockIdx.x * 64;

    for (int c = tid; c < 1024; c += 256) {
        int r = c >> 4;
        int k8 = (c & 15) << 3;
        int n = node0 + r;
        int nc = n < N ? n : N - 1;
        const float4* hp = (const float4*)(h + (size_t)nc * H + k8);
        float4 a = hp[0], b = hp[1];
        short8 v;
        v[0] = (short)f2bf(a.x); v[1] = (short)f2bf(a.y);
        v[2] = (short)f2bf(a.z); v[3] = (short)f2bf(a.w);
        v[4] = (short)f2bf(b.x); v[5] = (short)f2bf(b.y);
        v[6] = (short)f2bf(b.z); v[7] = (short)f2bf(b.w);
        *(short8*)(&hsb[r * XS_STRIDE + k8]) = v;
    }
    __syncthreads();

    int lane = tid & 63;
    int wv = tid >> 6;
    int am = lane & 15;
    int aq = lane >> 4;

    short8 ah[4];
    int arow = wv * 16 + am;
#pragma unroll
    for (int kc = 0; kc < 4; ++kc)
        ah[kc] = *(const short8*)(&hsb[arow * XS_STRIDE + kc * 32 + aq * 8]);

    floatx4 zero = {0.f, 0.f, 0.f, 0.f};
#pragma unroll
    for (int j = 0; j < 8; ++j) {
        floatx4 acc = zero;
#pragma unroll
        for (int kc = 0; kc < 4; ++kc) {
            short8 b = *(const short8*)(Wms + (size_t)(((j * 4 + kc) * 64 + lane)) * 8);
            acc = __builtin_amdgcn_mfma_f32_16x16x32_bf16(ah[kc], b, acc, 0, 0, 0);
        }
        int c = j * 16 + am;
        float bias = bm[c];
#pragma unroll
        for (int q = 0; q < 4; ++q) {
            int node = node0 + wv * 16 + aq * 4 + q;
            if (node < N) Xh[(size_t)node * H + c] = acc[q] + bias;
        }
    }
}

// ---------------------------------------------------------------------------
// Kernel B (CSR gather): messages[n] = sum_{e: dst=n} Xh[src_e] + emb[type_e]
// ---------------------------------------------------------------------------
__global__ __launch_bounds__(256) void gather_kernel(
    const float* __restrict__ Xh, const float* __restrict__ emb,
    const int* __restrict__ off, const int* __restrict__ packed,
    unsigned short* __restrict__ messages_b, int N)
{
    int n = blockIdx.x * 4 + (threadIdx.x >> 6);
    if (n >= N) return;
    int lane = threadIdx.x & 63;
    int b = off[n], e = off[n + 1];
    float ax = 0.f, ay = 0.f;
    for (int i = b; i < e; ++i) {
        int u = packed[i];
        int src = u & 0xffffff;
        int t = u >> 24;
        const float2 xv = *((const float2*)(Xh + (size_t)src * H) + lane);
        const float2 ev = *((const float2*)(emb + (size_t)t * H) + lane);
        ax += xv.x + ev.x;
        ay += xv.y + ev.y;
    }
    u32 o = (u32)f2bf(ax) | ((u32)f2bf(ay) << 16);
    *((u32*)(messages_b + (size_t)n * H) + lane) = o;
}

// ---------------------------------------------------------------------------
// Kernel C (MFMA): fused GRU. B loads coalesced via swizzled Wihs/Whhs:
// gate g, tile j -> jr = g*8 + j; frag at ((jr*4+kc)*64 + lane)*8.
// ---------------------------------------------------------------------------
__global__ __launch_bounds__(256) void gru_mfma_kernel(
    const unsigned short* __restrict__ messages_b, const float* __restrict__ h,
    const unsigned short* __restrict__ Wihs, const unsigned short* __restrict__ Whhs,
    const float* __restrict__ bih, const float* __restrict__ bhh,
    const int* __restrict__ numn, float* __restrict__ out, int N)
{
    __shared__ unsigned short xs[64 * XS_STRIDE];
    __shared__ unsigned short hsb[64 * XS_STRIDE];

    int tid = threadIdx.x;
    int node0 = blockIdx.x * 64;

    for (int c = tid; c < 1024; c += 256) {
        int r = c >> 4;
        int k8 = (c & 15) << 3;
        int n = node0 + r;
        int nc = n < N ? n : N - 1;
        short8 xv = *(const short8*)(messages_b + (size_t)nc * H + k8);
        const float4* hp = (const float4*)(h + (size_t)nc * H + k8);
        float4 h0 = hp[0], h1 = hp[1];
        short8 hv;
        hv[0] = (short)f2bf(h0.x); hv[1] = (short)f2bf(h0.y);
        hv[2] = (short)f2bf(h0.z); hv[3] = (short)f2bf(h0.w);
        hv[4] = (short)f2bf(h1.x); hv[5] = (short)f2bf(h1.y);
        hv[6] = (short)f2bf(h1.z); hv[7] = (short)f2bf(h1.w);
        *(short8*)(&xs[r * XS_STRIDE + k8]) = xv;
        *(short8*)(&hsb[r * XS_STRIDE + k8]) = hv;
    }
    __syncthreads();

    int lane = tid & 63;
    int wv = tid >> 6;
    int am = lane & 15;
    int aq = lane >> 4;

    short8 ax[4], ahf[4];
    int arow = wv * 16 + am;
#pragma unroll
    for (int kc = 0; kc < 4; ++kc) {
        ax[kc]  = *(const short8*)(&xs[arow * XS_STRIDE + kc * 32 + aq * 8]);
        ahf[kc] = *(const short8*)(&hsb[arow * XS_STRIDE + kc * 32 + aq * 8]);
    }

    int num_nodes = numn[0];
    floatx4 zero = {0.f, 0.f, 0.f, 0.f};

#pragma unroll
    for (int j = 0; j < 8; ++j) {
        floatx4 aIr = zero, aHr = zero, aIz = zero, aHz = zero, aIn = zero, aHn = zero;
#pragma unroll
        for (int kc = 0; kc < 4; ++kc) {
            size_t c_r = (size_t)(((0 * 8 + j) * 4 + kc) * 64 + lane) * 8;
            size_t c_z = (size_t)(((1 * 8 + j) * 4 + kc) * 64 + lane) * 8;
            size_t c_n = (size_t)(((2 * 8 + j) * 4 + kc) * 64 + lane) * 8;
            short8 bir = *(const short8*)(Wihs + c_r);
            short8 bhr = *(const short8*)(Whhs + c_r);
            short8 biz = *(const short8*)(Wihs + c_z);
            short8 bhz = *(const short8*)(Whhs + c_z);
            short8 bin = *(const short8*)(Wihs + c_n);
            short8 bhn = *(const short8*)(Whhs + c_n);
            aIr = __builtin_amdgcn_mfma_f32_16x16x32_bf16(ax[kc],  bir, aIr, 0, 0, 0);
            aHr = __builtin_amdgcn_mfma_f32_16x16x32_bf16(ahf[kc], bhr, aHr, 0, 0, 0);
            aIz = __builtin_amdgcn_mfma_f32_16x16x32_bf16(ax[kc],  biz, aIz, 0, 0, 0);
            aHz = __builtin_amdgcn_mfma_f32_16x16x32_bf16(ahf[kc], bhz, aHz, 0, 0, 0);
            aIn = __builtin_amdgcn_mfma_f32_16x16x32_bf16(ax[kc],  bin, aIn, 0, 0, 0);
            aHn = __builtin_amdgcn_mfma_f32_16x16x32_bf16(ahf[kc], bhn, aHn, 0, 0, 0);
        }
        int c = j * 16 + am;
        float b_ir = bih[c],       b_hr = bhh[c];
        float b_iz = bih[128 + c], b_hz = bhh[128 + c];
        float b_in = bih[256 + c], b_hn = bhh[256 + c];
#pragma unroll
        for (int q = 0; q < 4; ++q) {
            int m = aq * 4 + q;
            int node = node0 + wv * 16 + m;
            if (node < N) {
                float r  = sigmoid_f(aIr[q] + b_ir + aHr[q] + b_hr);
                float z  = sigmoid_f(aIz[q] + b_iz + aHz[q] + b_hz);
                float nv = tanh_f((aIn[q] + b_in) + r * (aHn[q] + b_hn));
                float hv = bf2f(hsb[(wv * 16 + m) * XS_STRIDE + c]);
                float o  = (1.0f - z) * nv + z * hv;
                out[(size_t)node * H + c] = (node < num_nodes) ? o : 0.0f;
            }
        }
    }
}

extern "C" void kernel_launch(void* const* d_in, const int* in_sizes, int n_in,
                              void* d_out, int out_size, void* d_ws, size_t ws_size,
                              hipStream_t stream) {
    const float* h    = (const float*)d_in[0];
    const int*  eidx  = (const int*)d_in[1];
    const int*  etype = (const int*)d_in[2];
    const int*  numn  = (const int*)d_in[3];
    const float* Wm   = (const float*)d_in[4];
    const float* bm   = (const float*)d_in[5];
    const float* emb  = (const float*)d_in[6];
    const float* Wih  = (const float*)d_in[7];
    const float* Whh  = (const float*)d_in[8];
    const float* bih  = (const float*)d_in[9];
    const float* bhh  = (const float*)d_in[10];

    int N = in_sizes[0] / H;
    int E = in_sizes[2];

    // ws layout:
    unsigned short* messages_b = (unsigned short*)d_ws;          // N*H bf16
    unsigned short* Wihs = messages_b + (size_t)N * H;           // 3*H*H (swizzled)
    unsigned short* Whhs = Wihs + 3 * H * H;                     // 3*H*H (swizzled)
    unsigned short* Wms  = Whhs + 3 * H * H;                     // H*H   (swizzled)
    int* deg    = (int*)(Wms + H * H);                           // N
    int* pos    = deg + N;                                       // N
    int* off    = pos + N;                                       // N+1
    int* packed = off + (N + 1);                                 // E
    int* tsum   = packed + E;                                    // SCAN_B*SCAN_T
    int* bsum   = tsum + SCAN_B * SCAN_T;                        // SCAN_B
    float* Xh   = (float*)d_out;                                 // scratch in d_out

    hipMemsetAsync(deg, 0, (size_t)N * sizeof(int), stream);

    convert_w_kernel<<<24, 256, 0, stream>>>(Wih, Whh, Wm, Wihs, Whhs, Wms);
    hist_kernel<<<(E + 255) / 256, 256, 0, stream>>>(eidx, deg, E);

    int ipt = (N + SCAN_B * SCAN_T - 1) / (SCAN_B * SCAN_T);
    scan_part_kernel<<<SCAN_B, SCAN_T, 0, stream>>>(deg, tsum, bsum, N, ipt);
    scan_mid_kernel<<<1, 64, 0, stream>>>(bsum, off, N);
    scan_final_kernel<<<SCAN_B, SCAN_T, 0, stream>>>(deg, tsum, bsum, off, pos, N, ipt);

    fill_kernel<<<(E + 255) / 256, 256, 0, stream>>>(eidx, etype, pos, packed, E);

    int nblk = (N + 63) / 64;
    xh_mfma_kernel<<<nblk, 256, 0, stream>>>(h, Wms, bm, Xh, N);
    gather_kernel<<<(N + 3) / 4, 256, 0, stream>>>(Xh, emb, off, packed, messages_b, N);
    gru_mfma_kernel<<<nblk, 256, 0, stream>>>(messages_b, h, Wihs, Whhs, bih, bhh,
                                              numn, (float*)d_out, N);
}

// Round 9
// 273.077 us; speedup vs baseline: 7.5181x; 1.0460x over previous
//
#include <hip/hip_runtime.h>
#include <math.h>

#define H 128
typedef unsigned int u32;
typedef __attribute__((ext_vector_type(8))) short short8;
typedef __attribute__((ext_vector_type(4))) float floatx4;

#define XS_STRIDE 136   // bf16 elems per padded row (128 + 8)

#define SCAN_B 64
#define SCAN_T 256

__device__ __forceinline__ float sigmoid_f(float x) {
    return 1.0f / (1.0f + __expf(-x));
}
__device__ __forceinline__ float tanh_f(float x) {
    float t = __expf(-2.0f * fabsf(x));
    float r = (1.0f - t) / (1.0f + t);
    return copysignf(r, x);
}
// f32 -> bf16 bits, round-to-nearest-even (finite inputs)
__device__ __forceinline__ unsigned short f2bf(float x) {
    u32 u = __float_as_uint(x);
    return (unsigned short)((u + 0x7fffu + ((u >> 16) & 1u)) >> 16);
}
__device__ __forceinline__ float bf2f(unsigned short s) {
    return __uint_as_float(((u32)s) << 16);
}
__device__ __forceinline__ float bf_lo32(u32 u) { return __uint_as_float(u << 16); }
__device__ __forceinline__ float bf_hi32(u32 u) { return __uint_as_float(u & 0xffff0000u); }

// ---------------------------------------------------------------------------
// Convert + SWIZZLE weights into MFMA B-fragment order (bf16):
// out[((jr*4+kc)*64 + l)*8 + i] = W[(jr*16 + (l&15))*H + kc*32 + (l>>4)*8 + i]
// ---------------------------------------------------------------------------
__global__ __launch_bounds__(256) void convert_w_kernel(
    const float* __restrict__ Wih, const float* __restrict__ Whh,
    const float* __restrict__ Wm,
    unsigned short* __restrict__ Wihs, unsigned short* __restrict__ Whhs,
    unsigned short* __restrict__ Wms)
{
    int idx = blockIdx.x * 256 + threadIdx.x;   // chunk-lane id
    if (idx >= 6144) return;
    int l  = idx & 63;
    int kc = (idx >> 6) & 3;
    int jr = idx >> 8;
    int m = l & 15, q = l >> 4;
    size_t srco = (size_t)(jr * 16 + m) * H + kc * 32 + q * 8;

    {
        const float4* s0 = (const float4*)(Wih + srco);
        float4 a = s0[0], b = s0[1];
        short8 v;
        v[0] = (short)f2bf(a.x); v[1] = (short)f2bf(a.y);
        v[2] = (short)f2bf(a.z); v[3] = (short)f2bf(a.w);
        v[4] = (short)f2bf(b.x); v[5] = (short)f2bf(b.y);
        v[6] = (short)f2bf(b.z); v[7] = (short)f2bf(b.w);
        *(short8*)(Wihs + (size_t)idx * 8) = v;
    }
    {
        const float4* s0 = (const float4*)(Whh + srco);
        float4 a = s0[0], b = s0[1];
        short8 v;
        v[0] = (short)f2bf(a.x); v[1] = (short)f2bf(a.y);
        v[2] = (short)f2bf(a.z); v[3] = (short)f2bf(a.w);
        v[4] = (short)f2bf(b.x); v[5] = (short)f2bf(b.y);
        v[6] = (short)f2bf(b.z); v[7] = (short)f2bf(b.w);
        *(short8*)(Whhs + (size_t)idx * 8) = v;
    }
    if (idx < 2048) {
        const float4* s0 = (const float4*)(Wm + srco);
        float4 a = s0[0], b = s0[1];
        short8 v;
        v[0] = (short)f2bf(a.x); v[1] = (short)f2bf(a.y);
        v[2] = (short)f2bf(a.z); v[3] = (short)f2bf(a.w);
        v[4] = (short)f2bf(b.x); v[5] = (short)f2bf(b.y);
        v[6] = (short)f2bf(b.z); v[7] = (short)f2bf(b.w);
        *(short8*)(Wms + (size_t)idx * 8) = v;
    }
}

// ---------------------------------------------------------------------------
// CSR build step 1: degree histogram over dst.
// ---------------------------------------------------------------------------
__global__ __launch_bounds__(256) void hist_kernel(
    const int* __restrict__ eidx, int* __restrict__ deg, int E)
{
    int e = blockIdx.x * 256 + threadIdx.x;
    if (e < E) atomicAdd(&deg[eidx[E + e]], 1);
}

// ---------------------------------------------------------------------------
// CSR build step 2a: per-thread chunk sums + per-block totals (parallel).
// ---------------------------------------------------------------------------
__global__ __launch_bounds__(SCAN_T) void scan_part_kernel(
    const int* __restrict__ deg, int* __restrict__ tsum,
    int* __restrict__ bsum, int N, int ipt)
{
    __shared__ int red[SCAN_T];
    int t = threadIdx.x;
    int g = blockIdx.x * SCAN_T + t;
    int s = g * ipt;
    int e = s + ipt < N ? s + ipt : N;
    int sum = 0;
    for (int i = s; i < e; ++i) sum += deg[i];
    tsum[g] = sum;
    red[t] = sum;
    __syncthreads();
    for (int d = SCAN_T / 2; d > 0; d >>= 1) {
        if (t < d) red[t] += red[t + d];
        __syncthreads();
    }
    if (t == 0) bsum[blockIdx.x] = red[0];
}

// ---------------------------------------------------------------------------
// CSR build step 2b: exclusive scan of the 64 block totals (tiny).
// ---------------------------------------------------------------------------
__global__ __launch_bounds__(64) void scan_mid_kernel(
    int* __restrict__ bsum, int* __restrict__ off, int N)
{
    if (threadIdx.x == 0) {
        int acc = 0;
        for (int b = 0; b < SCAN_B; ++b) { int v = bsum[b]; bsum[b] = acc; acc += v; }
        off[N] = acc;
    }
}

// ---------------------------------------------------------------------------
// CSR build step 2c: block-level scan of thread sums + write off/pos.
// ---------------------------------------------------------------------------
__global__ __launch_bounds__(SCAN_T) void scan_final_kernel(
    const int* __restrict__ deg, const int* __restrict__ tsum,
    const int* __restrict__ bsum, int* __restrict__ off,
    int* __restrict__ pos, int N, int ipt)
{
    __shared__ int part[SCAN_T];
    int t = threadIdx.x;
    int g = blockIdx.x * SCAN_T + t;
    part[t] = tsum[g];
    __syncthreads();
    for (int d = 1; d < SCAN_T; d <<= 1) {
        int v = (t >= d) ? part[t - d] : 0;
        __syncthreads();
        part[t] += v;
        __syncthreads();
    }
    int base = bsum[blockIdx.x] + ((t == 0) ? 0 : part[t - 1]);
    int s = g * ipt;
    int e = s + ipt < N ? s + ipt : N;
    for (int i = s; i < e; ++i) {
        off[i] = base;
        pos[i] = base;
        base += deg[i];
    }
}

// ---------------------------------------------------------------------------
// CSR build step 3: scatter edge ids into slots; pack src|type into one int.
// ---------------------------------------------------------------------------
__global__ __launch_bounds__(256) void fill_kernel(
    const int* __restrict__ eidx, const int* __restrict__ etype,
    int* __restrict__ pos, int* __restrict__ packed, int E)
{
    int e = blockIdx.x * 256 + threadIdx.x;
    if (e >= E) return;
    int src = eidx[e];
    int dst = eidx[E + e];
    int t = etype[e];
    t = t < 0 ? 0 : (t > 8 ? 8 : t);
    int p = atomicAdd(&pos[dst], 1);
    packed[p] = src | (t << 24);
}

// ---------------------------------------------------------------------------
// Kernel A (MFMA): Xh[n][c] = sum_k h[n][k] * Wm[c][k] + bm[c] -> bf16 out.
// ---------------------------------------------------------------------------
__global__ __launch_bounds__(256) void xh_mfma_kernel(
    const float* __restrict__ h, const unsigned short* __restrict__ Wms,
    const float* __restrict__ bm, unsigned short* __restrict__ Xh_b, int N)
{
    __shared__ unsigned short hsb[64 * XS_STRIDE];

    int tid = threadIdx.x;
    int node0 = blockIdx.x * 64;

    for (int c = tid; c < 1024; c += 256) {
        int r = c >> 4;
        int k8 = (c & 15) << 3;
        int n = node0 + r;
        int nc = n < N ? n : N - 1;
        const float4* hp = (const float4*)(h + (size_t)nc * H + k8);
        float4 a = hp[0], b = hp[1];
        short8 v;
        v[0] = (short)f2bf(a.x); v[1] = (short)f2bf(a.y);
        v[2] = (short)f2bf(a.z); v[3] = (short)f2bf(a.w);
        v[4] = (short)f2bf(b.x); v[5] = (short)f2bf(b.y);
        v[6] = (short)f2bf(b.z); v[7] = (short)f2bf(b.w);
        *(short8*)(&hsb[r * XS_STRIDE + k8]) = v;
    }
    __syncthreads();

    int lane = tid & 63;
    int wv = tid >> 6;
    int am = lane & 15;
    int aq = lane >> 4;

    short8 ah[4];
    int arow = wv * 16 + am;
#pragma unroll
    for (int kc = 0; kc < 4; ++kc)
        ah[kc] = *(const short8*)(&hsb[arow * XS_STRIDE + kc * 32 + aq * 8]);

    floatx4 zero = {0.f, 0.f, 0.f, 0.f};
#pragma unroll
    for (int j = 0; j < 8; ++j) {
        floatx4 acc = zero;
#pragma unroll
        for (int kc = 0; kc < 4; ++kc) {
            short8 b = *(const short8*)(Wms + (size_t)(((j * 4 + kc) * 64 + lane)) * 8);
            acc = __builtin_amdgcn_mfma_f32_16x16x32_bf16(ah[kc], b, acc, 0, 0, 0);
        }
        int c = j * 16 + am;
        float bias = bm[c];
#pragma unroll
        for (int q = 0; q < 4; ++q) {
            int node = node0 + wv * 16 + aq * 4 + q;
            if (node < N) Xh_b[(size_t)node * H + c] = f2bf(acc[q] + bias);
        }
    }
}

// ---------------------------------------------------------------------------
// Kernel B (CSR gather): messages[n] = sum_{e: dst=n} Xh[src_e] + emb[type_e]
// Xh rows are bf16 (256 B/row): lane reads one u32 = 2 cols. f32 accumulate.
// ---------------------------------------------------------------------------
__global__ __launch_bounds__(256) void gather_kernel(
    const unsigned short* __restrict__ Xh_b, const float* __restrict__ emb,
    const int* __restrict__ off, const int* __restrict__ packed,
    unsigned short* __restrict__ messages_b, int N)
{
    int n = blockIdx.x * 4 + (threadIdx.x >> 6);
    if (n >= N) return;
    int lane = threadIdx.x & 63;
    int b = off[n], e = off[n + 1];
    float ax = 0.f, ay = 0.f;
    for (int i = b; i < e; ++i) {
        int u = packed[i];
        int src = u & 0xffffff;
        int t = u >> 24;
        u32 xv = *((const u32*)(Xh_b + (size_t)src * H) + lane);
        const float2 ev = *((const float2*)(emb + (size_t)t * H) + lane);
        ax += bf_lo32(xv) + ev.x;
        ay += bf_hi32(xv) + ev.y;
    }
    u32 o = (u32)f2bf(ax) | ((u32)f2bf(ay) << 16);
    *((u32*)(messages_b + (size_t)n * H) + lane) = o;
}

// ---------------------------------------------------------------------------
// Kernel C (MFMA): fused GRU (B loads via swizzled Wihs/Whhs).
// ---------------------------------------------------------------------------
__global__ __launch_bounds__(256) void gru_mfma_kernel(
    const unsigned short* __restrict__ messages_b, const float* __restrict__ h,
    const unsigned short* __restrict__ Wihs, const unsigned short* __restrict__ Whhs,
    const float* __restrict__ bih, const float* __restrict__ bhh,
    const int* __restrict__ numn, float* __restrict__ out, int N)
{
    __shared__ unsigned short xs[64 * XS_STRIDE];
    __shared__ unsigned short hsb[64 * XS_STRIDE];

    int tid = threadIdx.x;
    int node0 = blockIdx.x * 64;

    for (int c = tid; c < 1024; c += 256) {
        int r = c >> 4;
        int k8 = (c & 15) << 3;
        int n = node0 + r;
        int nc = n < N ? n : N - 1;
        short8 xv = *(const short8*)(messages_b + (size_t)nc * H + k8);
        const float4* hp = (const float4*)(h + (size_t)nc * H + k8);
        float4 h0 = hp[0], h1 = hp[1];
        short8 hv;
        hv[0] = (short)f2bf(h0.x); hv[1] = (short)f2bf(h0.y);
        hv[2] = (short)f2bf(h0.z); hv[3] = (short)f2bf(h0.w);
        hv[4] = (short)f2bf(h1.x); hv[5] = (short)f2bf(h1.y);
        hv[6] = (short)f2bf(h1.z); hv[7] = (short)f2bf(h1.w);
        *(short8*)(&xs[r * XS_STRIDE + k8]) = xv;
        *(short8*)(&hsb[r * XS_STRIDE + k8]) = hv;
    }
    __syncthreads();

    int lane = tid & 63;
    int wv = tid >> 6;
    int am = lane & 15;
    int aq = lane >> 4;

    short8 ax[4], ahf[4];
    int arow = wv * 16 + am;
#pragma unroll
    for (int kc = 0; kc < 4; ++kc) {
        ax[kc]  = *(const short8*)(&xs[arow * XS_STRIDE + kc * 32 + aq * 8]);
        ahf[kc] = *(const short8*)(&hsb[arow * XS_STRIDE + kc * 32 + aq * 8]);
    }

    int num_nodes = numn[0];
    floatx4 zero = {0.f, 0.f, 0.f, 0.f};

#pragma unroll
    for (int j = 0; j < 8; ++j) {
        floatx4 aIr = zero, aHr = zero, aIz = zero, aHz = zero, aIn = zero, aHn = zero;
#pragma unroll
        for (int kc = 0; kc < 4; ++kc) {
            size_t c_r = (size_t)(((0 * 8 + j) * 4 + kc) * 64 + lane) * 8;
            size_t c_z = (size_t)(((1 * 8 + j) * 4 + kc) * 64 + lane) * 8;
            size_t c_n = (size_t)(((2 * 8 + j) * 4 + kc) * 64 + lane) * 8;
            short8 bir = *(const short8*)(Wihs + c_r);
            short8 bhr = *(const short8*)(Whhs + c_r);
            short8 biz = *(const short8*)(Wihs + c_z);
            short8 bhz = *(const short8*)(Whhs + c_z);
            short8 bin = *(const short8*)(Wihs + c_n);
            short8 bhn = *(const short8*)(Whhs + c_n);
            aIr = __builtin_amdgcn_mfma_f32_16x16x32_bf16(ax[kc],  bir, aIr, 0, 0, 0);
            aHr = __builtin_amdgcn_mfma_f32_16x16x32_bf16(ahf[kc], bhr, aHr, 0, 0, 0);
            aIz = __builtin_amdgcn_mfma_f32_16x16x32_bf16(ax[kc],  biz, aIz, 0, 0, 0);
            aHz = __builtin_amdgcn_mfma_f32_16x16x32_bf16(ahf[kc], bhz, aHz, 0, 0, 0);
            aIn = __builtin_amdgcn_mfma_f32_16x16x32_bf16(ax[kc],  bin, aIn, 0, 0, 0);
            aHn = __builtin_amdgcn_mfma_f32_16x16x32_bf16(ahf[kc], bhn, aHn, 0, 0, 0);
        }
        int c = j * 16 + am;
        float b_ir = bih[c],       b_hr = bhh[c];
        float b_iz = bih[128 + c], b_hz = bhh[128 + c];
        float b_in = bih[256 + c], b_hn = bhh[256 + c];
#pragma unroll
        for (int q = 0; q < 4; ++q) {
            int m = aq * 4 + q;
            int node = node0 + wv * 16 + m;
            if (node < N) {
                float r  = sigmoid_f(aIr[q] + b_ir + aHr[q] + b_hr);
                float z  = sigmoid_f(aIz[q] + b_iz + aHz[q] + b_hz);
                float nv = tanh_f((aIn[q] + b_in) + r * (aHn[q] + b_hn));
                float hv = bf2f(hsb[(wv * 16 + m) * XS_STRIDE + c]);
                float o  = (1.0f - z) * nv + z * hv;
                out[(size_t)node * H + c] = (node < num_nodes) ? o : 0.0f;
            }
        }
    }
}

extern "C" void kernel_launch(void* const* d_in, const int* in_sizes, int n_in,
                              void* d_out, int out_size, void* d_ws, size_t ws_size,
                              hipStream_t stream) {
    const float* h    = (const float*)d_in[0];
    const int*  eidx  = (const int*)d_in[1];
    const int*  etype = (const int*)d_in[2];
    const int*  numn  = (const int*)d_in[3];
    const float* Wm   = (const float*)d_in[4];
    const float* bm   = (const float*)d_in[5];
    const float* emb  = (const float*)d_in[6];
    const float* Wih  = (const float*)d_in[7];
    const float* Whh  = (const float*)d_in[8];
    const float* bih  = (const float*)d_in[9];
    const float* bhh  = (const float*)d_in[10];

    int N = in_sizes[0] / H;
    int E = in_sizes[2];

    // ws layout:
    unsigned short* messages_b = (unsigned short*)d_ws;          // N*H bf16
    unsigned short* Wihs = messages_b + (size_t)N * H;           // 3*H*H (swizzled)
    unsigned short* Whhs = Wihs + 3 * H * H;                     // 3*H*H (swizzled)
    unsigned short* Wms  = Whhs + 3 * H * H;                     // H*H   (swizzled)
    int* deg    = (int*)(Wms + H * H);                           // N
    int* pos    = deg + N;                                       // N
    int* off    = pos + N;                                       // N+1
    int* packed = off + (N + 1);                                 // E
    int* tsum   = packed + E;                                    // SCAN_B*SCAN_T
    int* bsum   = tsum + SCAN_B * SCAN_T;                        // SCAN_B
    unsigned short* Xh_b = (unsigned short*)d_out;               // N*H bf16 scratch in d_out

    hipMemsetAsync(deg, 0, (size_t)N * sizeof(int), stream);

    convert_w_kernel<<<24, 256, 0, stream>>>(Wih, Whh, Wm, Wihs, Whhs, Wms);
    hist_kernel<<<(E + 255) / 256, 256, 0, stream>>>(eidx, deg, E);

    int ipt = (N + SCAN_B * SCAN_T - 1) / (SCAN_B * SCAN_T);
    scan_part_kernel<<<SCAN_B, SCAN_T, 0, stream>>>(deg, tsum, bsum, N, ipt);
    scan_mid_kernel<<<1, 64, 0, stream>>>(bsum, off, N);
    scan_final_kernel<<<SCAN_B, SCAN_T, 0, stream>>>(deg, tsum, bsum, off, pos, N, ipt);

    fill_kernel<<<(E + 255) / 256, 256, 0, stream>>>(eidx, etype, pos, packed, E);

    int nblk = (N + 63) / 64;
    xh_mfma_kernel<<<nblk, 256, 0, stream>>>(h, Wms, bm, Xh_b, N);
    gather_kernel<<<(N + 3) / 4, 256, 0, stream>>>(Xh_b, emb, off, packed, messages_b, N);
    gru_mfma_kernel<<<nblk, 256, 0, stream>>>(messages_b, h, Wihs, Whhs, bih, bhh,
                                              numn, (float*)d_out, N);
}

// Round 10
// 250.657 us; speedup vs baseline: 8.1905x; 1.0894x over previous
//
#include <hip/hip_runtime.h>
#include <math.h>

#define H 128
typedef unsigned int u32;
typedef unsigned long long u64;
typedef __attribute__((ext_vector_type(8))) short short8;
typedef __attribute__((ext_vector_type(4))) float floatx4;

#define XS_STRIDE 136   // bf16 elems per padded row (128 + 8)

#define SCAN_B 64
#define SCAN_T 256

__device__ __forceinline__ float sigmoid_f(float x) {
    return 1.0f / (1.0f + __expf(-x));
}
__device__ __forceinline__ float tanh_f(float x) {
    float t = __expf(-2.0f * fabsf(x));
    float r = (1.0f - t) / (1.0f + t);
    return copysignf(r, x);
}
// f32 -> bf16 bits, round-to-nearest-even (finite inputs)
__device__ __forceinline__ unsigned short f2bf(float x) {
    u32 u = __float_as_uint(x);
    return (unsigned short)((u + 0x7fffu + ((u >> 16) & 1u)) >> 16);
}
__device__ __forceinline__ float bf2f(unsigned short s) {
    return __uint_as_float(((u32)s) << 16);
}
__device__ __forceinline__ float bf_lo32(u32 u) { return __uint_as_float(u << 16); }
__device__ __forceinline__ float bf_hi32(u32 u) { return __uint_as_float(u & 0xffff0000u); }

// ---------------------------------------------------------------------------
// Convert + SWIZZLE weights into MFMA B-fragment order (bf16):
// out[((jr*4+kc)*64 + l)*8 + i] = W[(jr*16 + (l&15))*H + kc*32 + (l>>4)*8 + i]
// ---------------------------------------------------------------------------
__global__ __launch_bounds__(256) void convert_w_kernel(
    const float* __restrict__ Wih, const float* __restrict__ Whh,
    const float* __restrict__ Wm,
    unsigned short* __restrict__ Wihs, unsigned short* __restrict__ Whhs,
    unsigned short* __restrict__ Wms)
{
    int idx = blockIdx.x * 256 + threadIdx.x;   // chunk-lane id
    if (idx >= 6144) return;
    int l  = idx & 63;
    int kc = (idx >> 6) & 3;
    int jr = idx >> 8;
    int m = l & 15, q = l >> 4;
    size_t srco = (size_t)(jr * 16 + m) * H + kc * 32 + q * 8;

    {
        const float4* s0 = (const float4*)(Wih + srco);
        float4 a = s0[0], b = s0[1];
        short8 v;
        v[0] = (short)f2bf(a.x); v[1] = (short)f2bf(a.y);
        v[2] = (short)f2bf(a.z); v[3] = (short)f2bf(a.w);
        v[4] = (short)f2bf(b.x); v[5] = (short)f2bf(b.y);
        v[6] = (short)f2bf(b.z); v[7] = (short)f2bf(b.w);
        *(short8*)(Wihs + (size_t)idx * 8) = v;
    }
    {
        const float4* s0 = (const float4*)(Whh + srco);
        float4 a = s0[0], b = s0[1];
        short8 v;
        v[0] = (short)f2bf(a.x); v[1] = (short)f2bf(a.y);
        v[2] = (short)f2bf(a.z); v[3] = (short)f2bf(a.w);
        v[4] = (short)f2bf(b.x); v[5] = (short)f2bf(b.y);
        v[6] = (short)f2bf(b.z); v[7] = (short)f2bf(b.w);
        *(short8*)(Whhs + (size_t)idx * 8) = v;
    }
    if (idx < 2048) {
        const float4* s0 = (const float4*)(Wm + srco);
        float4 a = s0[0], b = s0[1];
        short8 v;
        v[0] = (short)f2bf(a.x); v[1] = (short)f2bf(a.y);
        v[2] = (short)f2bf(a.z); v[3] = (short)f2bf(a.w);
        v[4] = (short)f2bf(b.x); v[5] = (short)f2bf(b.y);
        v[6] = (short)f2bf(b.z); v[7] = (short)f2bf(b.w);
        *(short8*)(Wms + (size_t)idx * 8) = v;
    }
}

// ---------------------------------------------------------------------------
// CSR build step 1: degree histogram over dst.
// ---------------------------------------------------------------------------
__global__ __launch_bounds__(256) void hist_kernel(
    const int* __restrict__ eidx, int* __restrict__ deg, int E)
{
    int e = blockIdx.x * 256 + threadIdx.x;
    if (e < E) atomicAdd(&deg[eidx[E + e]], 1);
}

// ---------------------------------------------------------------------------
// CSR build step 2a: per-thread chunk sums + per-block totals (parallel).
// ---------------------------------------------------------------------------
__global__ __launch_bounds__(SCAN_T) void scan_part_kernel(
    const int* __restrict__ deg, int* __restrict__ tsum,
    int* __restrict__ bsum, int N, int ipt)
{
    __shared__ int red[SCAN_T];
    int t = threadIdx.x;
    int g = blockIdx.x * SCAN_T + t;
    int s = g * ipt;
    int e = s + ipt < N ? s + ipt : N;
    int sum = 0;
    for (int i = s; i < e; ++i) sum += deg[i];
    tsum[g] = sum;
    red[t] = sum;
    __syncthreads();
    for (int d = SCAN_T / 2; d > 0; d >>= 1) {
        if (t < d) red[t] += red[t + d];
        __syncthreads();
    }
    if (t == 0) bsum[blockIdx.x] = red[0];
}

// ---------------------------------------------------------------------------
// CSR build step 2b (merged): per-block scan of raw bsum + thread sums,
// then write off/pos. Block 0 also writes off[N]. One dispatch fewer.
// ---------------------------------------------------------------------------
__global__ __launch_bounds__(SCAN_T) void scan_final_kernel(
    const int* __restrict__ deg, const int* __restrict__ tsum,
    const int* __restrict__ bsum, int* __restrict__ off,
    int* __restrict__ pos, int N, int ipt)
{
    __shared__ int part[SCAN_T];
    __shared__ int bpre[SCAN_B + 1];
    int t = threadIdx.x;
    if (t == 0) {
        int acc = 0;
        for (int b2 = 0; b2 < SCAN_B; ++b2) { bpre[b2] = acc; acc += bsum[b2]; }
        bpre[SCAN_B] = acc;
        if (blockIdx.x == 0) off[N] = acc;
    }
    int g = blockIdx.x * SCAN_T + t;
    part[t] = tsum[g];
    __syncthreads();
    for (int d = 1; d < SCAN_T; d <<= 1) {
        int v = (t >= d) ? part[t - d] : 0;
        __syncthreads();
        part[t] += v;
        __syncthreads();
    }
    int base = bpre[blockIdx.x] + ((t == 0) ? 0 : part[t - 1]);
    int s = g * ipt;
    int e = s + ipt < N ? s + ipt : N;
    for (int i = s; i < e; ++i) {
        off[i] = base;
        pos[i] = base;
        base += deg[i];
    }
}

// ---------------------------------------------------------------------------
// CSR build step 3: scatter edge ids into slots; pack src|type into one int.
// ---------------------------------------------------------------------------
__global__ __launch_bounds__(256) void fill_kernel(
    const int* __restrict__ eidx, const int* __restrict__ etype,
    int* __restrict__ pos, int* __restrict__ packed, int E)
{
    int e = blockIdx.x * 256 + threadIdx.x;
    if (e >= E) return;
    int src = eidx[e];
    int dst = eidx[E + e];
    int t = etype[e];
    t = t < 0 ? 0 : (t > 8 ? 8 : t);
    int p = atomicAdd(&pos[dst], 1);
    packed[p] = src | (t << 24);
}

// ---------------------------------------------------------------------------
// Kernel A (MFMA): Xh[n][c] = sum_k h[n][k] * Wm[c][k] + bm[c] -> bf16 out.
// ---------------------------------------------------------------------------
__global__ __launch_bounds__(256) void xh_mfma_kernel(
    const float* __restrict__ h, const unsigned short* __restrict__ Wms,
    const float* __restrict__ bm, unsigned short* __restrict__ Xh_b, int N)
{
    __shared__ unsigned short hsb[64 * XS_STRIDE];

    int tid = threadIdx.x;
    int node0 = blockIdx.x * 64;

    for (int c = tid; c < 1024; c += 256) {
        int r = c >> 4;
        int k8 = (c & 15) << 3;
        int n = node0 + r;
        int nc = n < N ? n : N - 1;
        const float4* hp = (const float4*)(h + (size_t)nc * H + k8);
        float4 a = hp[0], b = hp[1];
        short8 v;
        v[0] = (short)f2bf(a.x); v[1] = (short)f2bf(a.y);
        v[2] = (short)f2bf(a.z); v[3] = (short)f2bf(a.w);
        v[4] = (short)f2bf(b.x); v[5] = (short)f2bf(b.y);
        v[6] = (short)f2bf(b.z); v[7] = (short)f2bf(b.w);
        *(short8*)(&hsb[r * XS_STRIDE + k8]) = v;
    }
    __syncthreads();

    int lane = tid & 63;
    int wv = tid >> 6;
    int am = lane & 15;
    int aq = lane >> 4;

    short8 ah[4];
    int arow = wv * 16 + am;
#pragma unroll
    for (int kc = 0; kc < 4; ++kc)
        ah[kc] = *(const short8*)(&hsb[arow * XS_STRIDE + kc * 32 + aq * 8]);

    floatx4 zero = {0.f, 0.f, 0.f, 0.f};
#pragma unroll
    for (int j = 0; j < 8; ++j) {
        floatx4 acc = zero;
#pragma unroll
        for (int kc = 0; kc < 4; ++kc) {
            short8 b = *(const short8*)(Wms + (size_t)(((j * 4 + kc) * 64 + lane)) * 8);
            acc = __builtin_amdgcn_mfma_f32_16x16x32_bf16(ah[kc], b, acc, 0, 0, 0);
        }
        int c = j * 16 + am;
        float bias = bm[c];
#pragma unroll
        for (int q = 0; q < 4; ++q) {
            int node = node0 + wv * 16 + aq * 4 + q;
            if (node < N) Xh_b[(size_t)node * H + c] = f2bf(acc[q] + bias);
        }
    }
}

// ---------------------------------------------------------------------------
// Kernel B (CSR gather): messages[n] = sum_{e: dst=n} Xh[src_e] + emb[type_e]
// 4x unrolled edge loop (4 row loads in flight). emb handled via packed
// 7-bit-per-type counters (degree < 128), applied once at the end.
// ---------------------------------------------------------------------------
__global__ __launch_bounds__(256) void gather_kernel(
    const unsigned short* __restrict__ Xh_b, const float* __restrict__ emb,
    const int* __restrict__ off, const int* __restrict__ packed,
    unsigned short* __restrict__ messages_b, int N)
{
    int n = blockIdx.x * 4 + (threadIdx.x >> 6);
    if (n >= N) return;
    int lane = threadIdx.x & 63;
    int b = off[n], e = off[n + 1];
    float ax = 0.f, ay = 0.f;
    u64 cnt = 0;
    int i = b;
    for (; i + 4 <= e; i += 4) {
        int u0 = packed[i + 0];
        int u1 = packed[i + 1];
        int u2 = packed[i + 2];
        int u3 = packed[i + 3];
        u32 x0 = *((const u32*)(Xh_b + (size_t)(u0 & 0xffffff) * H) + lane);
        u32 x1 = *((const u32*)(Xh_b + (size_t)(u1 & 0xffffff) * H) + lane);
        u32 x2 = *((const u32*)(Xh_b + (size_t)(u2 & 0xffffff) * H) + lane);
        u32 x3 = *((const u32*)(Xh_b + (size_t)(u3 & 0xffffff) * H) + lane);
        cnt += (1ull << (7 * (u0 >> 24))) + (1ull << (7 * (u1 >> 24)))
             + (1ull << (7 * (u2 >> 24))) + (1ull << (7 * (u3 >> 24)));
        ax += bf_lo32(x0) + bf_lo32(x1) + bf_lo32(x2) + bf_lo32(x3);
        ay += bf_hi32(x0) + bf_hi32(x1) + bf_hi32(x2) + bf_hi32(x3);
    }
    for (; i < e; ++i) {
        int u = packed[i];
        u32 x = *((const u32*)(Xh_b + (size_t)(u & 0xffffff) * H) + lane);
        cnt += 1ull << (7 * (u >> 24));
        ax += bf_lo32(x);
        ay += bf_hi32(x);
    }
#pragma unroll
    for (int t = 0; t < 9; ++t) {
        float c = (float)((u32)(cnt >> (7 * t)) & 127u);
        const float2 ev = *((const float2*)(emb + (size_t)t * H) + lane);
        ax += c * ev.x;
        ay += c * ev.y;
    }
    u32 o = (u32)f2bf(ax) | ((u32)f2bf(ay) << 16);
    *((u32*)(messages_b + (size_t)n * H) + lane) = o;
}

// ---------------------------------------------------------------------------
// Kernel C (MFMA): fused GRU (B loads via swizzled Wihs/Whhs).
// ---------------------------------------------------------------------------
__global__ __launch_bounds__(256) void gru_mfma_kernel(
    const unsigned short* __restrict__ messages_b, const float* __restrict__ h,
    const unsigned short* __restrict__ Wihs, const unsigned short* __restrict__ Whhs,
    const float* __restrict__ bih, const float* __restrict__ bhh,
    const int* __restrict__ numn, float* __restrict__ out, int N)
{
    __shared__ unsigned short xs[64 * XS_STRIDE];
    __shared__ unsigned short hsb[64 * XS_STRIDE];

    int tid = threadIdx.x;
    int node0 = blockIdx.x * 64;

    for (int c = tid; c < 1024; c += 256) {
        int r = c >> 4;
        int k8 = (c & 15) << 3;
        int n = node0 + r;
        int nc = n < N ? n : N - 1;
        short8 xv = *(const short8*)(messages_b + (size_t)nc * H + k8);
        const float4* hp = (const float4*)(h + (size_t)nc * H + k8);
        float4 h0 = hp[0], h1 = hp[1];
        short8 hv;
        hv[0] = (short)f2bf(h0.x); hv[1] = (short)f2bf(h0.y);
        hv[2] = (short)f2bf(h0.z); hv[3] = (short)f2bf(h0.w);
        hv[4] = (short)f2bf(h1.x); hv[5] = (short)f2bf(h1.y);
        hv[6] = (short)f2bf(h1.z); hv[7] = (short)f2bf(h1.w);
        *(short8*)(&xs[r * XS_STRIDE + k8]) = xv;
        *(short8*)(&hsb[r * XS_STRIDE + k8]) = hv;
    }
    __syncthreads();

    int lane = tid & 63;
    int wv = tid >> 6;
    int am = lane & 15;
    int aq = lane >> 4;

    short8 ax[4], ahf[4];
    int arow = wv * 16 + am;
#pragma unroll
    for (int kc = 0; kc < 4; ++kc) {
        ax[kc]  = *(const short8*)(&xs[arow * XS_STRIDE + kc * 32 + aq * 8]);
        ahf[kc] = *(const short8*)(&hsb[arow * XS_STRIDE + kc * 32 + aq * 8]);
    }

    int num_nodes = numn[0];
    floatx4 zero = {0.f, 0.f, 0.f, 0.f};

#pragma unroll
    for (int j = 0; j < 8; ++j) {
        floatx4 aIr = zero, aHr = zero, aIz = zero, aHz = zero, aIn = zero, aHn = zero;
#pragma unroll
        for (int kc = 0; kc < 4; ++kc) {
            size_t c_r = (size_t)(((0 * 8 + j) * 4 + kc) * 64 + lane) * 8;
            size_t c_z = (size_t)(((1 * 8 + j) * 4 + kc) * 64 + lane) * 8;
            size_t c_n = (size_t)(((2 * 8 + j) * 4 + kc) * 64 + lane) * 8;
            short8 bir = *(const short8*)(Wihs + c_r);
            short8 bhr = *(const short8*)(Whhs + c_r);
            short8 biz = *(const short8*)(Wihs + c_z);
            short8 bhz = *(const short8*)(Whhs + c_z);
            short8 bin = *(const short8*)(Wihs + c_n);
            short8 bhn = *(const short8*)(Whhs + c_n);
            aIr = __builtin_amdgcn_mfma_f32_16x16x32_bf16(ax[kc],  bir, aIr, 0, 0, 0);
            aHr = __builtin_amdgcn_mfma_f32_16x16x32_bf16(ahf[kc], bhr, aHr, 0, 0, 0);
            aIz = __builtin_amdgcn_mfma_f32_16x16x32_bf16(ax[kc],  biz, aIz, 0, 0, 0);
            aHz = __builtin_amdgcn_mfma_f32_16x16x32_bf16(ahf[kc], bhz, aHz, 0, 0, 0);
            aIn = __builtin_amdgcn_mfma_f32_16x16x32_bf16(ax[kc],  bin, aIn, 0, 0, 0);
            aHn = __builtin_amdgcn_mfma_f32_16x16x32_bf16(ahf[kc], bhn, aHn, 0, 0, 0);
        }
        int c = j * 16 + am;
        float b_ir = bih[c],       b_hr = bhh[c];
        float b_iz = bih[128 + c], b_hz = bhh[128 + c];
        float b_in = bih[256 + c], b_hn = bhh[256 + c];
#pragma unroll
        for (int q = 0; q < 4; ++q) {
            int m = aq * 4 + q;
            int node = node0 + wv * 16 + m;
            if (node < N) {
                float r  = sigmoid_f(aIr[q] + b_ir + aHr[q] + b_hr);
                float z  = sigmoid_f(aIz[q] + b_iz + aHz[q] + b_hz);
                float nv = tanh_f((aIn[q] + b_in) + r * (aHn[q] + b_hn));
                float hv = bf2f(hsb[(wv * 16 + m) * XS_STRIDE + c]);
                float o  = (1.0f - z) * nv + z * hv;
                out[(size_t)node * H + c] = (node < num_nodes) ? o : 0.0f;
            }
        }
    }
}

extern "C" void kernel_launch(void* const* d_in, const int* in_sizes, int n_in,
                              void* d_out, int out_size, void* d_ws, size_t ws_size,
                              hipStream_t stream) {
    const float* h    = (const float*)d_in[0];
    const int*  eidx  = (const int*)d_in[1];
    const int*  etype = (const int*)d_in[2];
    const int*  numn  = (const int*)d_in[3];
    const float* Wm   = (const float*)d_in[4];
    const float* bm   = (const float*)d_in[5];
    const float* emb  = (const float*)d_in[6];
    const float* Wih  = (const float*)d_in[7];
    const float* Whh  = (const float*)d_in[8];
    const float* bih  = (const float*)d_in[9];
    const float* bhh  = (const float*)d_in[10];

    int N = in_sizes[0] / H;
    int E = in_sizes[2];

    // ws layout:
    unsigned short* messages_b = (unsigned short*)d_ws;          // N*H bf16
    unsigned short* Wihs = messages_b + (size_t)N * H;           // 3*H*H (swizzled)
    unsigned short* Whhs = Wihs + 3 * H * H;                     // 3*H*H (swizzled)
    unsigned short* Wms  = Whhs + 3 * H * H;                     // H*H   (swizzled)
    int* deg    = (int*)(Wms + H * H);                           // N
    int* pos    = deg + N;                                       // N
    int* off    = pos + N;                                       // N+1
    int* packed = off + (N + 1);                                 // E
    int* tsum   = packed + E;                                    // SCAN_B*SCAN_T
    int* bsum   = tsum + SCAN_B * SCAN_T;                        // SCAN_B
    unsigned short* Xh_b = (unsigned short*)d_out;               // N*H bf16 scratch in d_out

    hipMemsetAsync(deg, 0, (size_t)N * sizeof(int), stream);

    convert_w_kernel<<<24, 256, 0, stream>>>(Wih, Whh, Wm, Wihs, Whhs, Wms);
    hist_kernel<<<(E + 255) / 256, 256, 0, stream>>>(eidx, deg, E);

    int ipt = (N + SCAN_B * SCAN_T - 1) / (SCAN_B * SCAN_T);
    scan_part_kernel<<<SCAN_B, SCAN_T, 0, stream>>>(deg, tsum, bsum, N, ipt);
    scan_final_kernel<<<SCAN_B, SCAN_T, 0, stream>>>(deg, tsum, bsum, off, pos, N, ipt);

    fill_kernel<<<(E + 255) / 256, 256, 0, stream>>>(eidx, etype, pos, packed, E);

    int nblk = (N + 63) / 64;
    xh_mfma_kernel<<<nblk, 256, 0, stream>>>(h, Wms, bm, Xh_b, N);
    gather_kernel<<<(N + 3) / 4, 256, 0, stream>>>(Xh_b, emb, off, packed, messages_b, N);
    gru_mfma_kernel<<<nblk, 256, 0, stream>>>(messages_b, h, Wihs, Whhs, bih, bhh,
                                              numn, (float*)d_out, N);
}

// Round 11
// 249.425 us; speedup vs baseline: 8.2310x; 1.0049x over previous
//
#include <hip/hip_runtime.h>
#include <math.h>

#define H 128
typedef unsigned int u32;
typedef unsigned long long u64;
typedef __attribute__((ext_vector_type(8))) short short8;
typedef __attribute__((ext_vector_type(4))) float floatx4;

#define XS_STRIDE 136   // bf16 elems per padded row (128 + 8)

#define SCAN_B 64
#define SCAN_T 256

__device__ __forceinline__ float sigmoid_f(float x) {
    return 1.0f / (1.0f + __expf(-x));
}
__device__ __forceinline__ float tanh_f(float x) {
    float t = __expf(-2.0f * fabsf(x));
    float r = (1.0f - t) / (1.0f + t);
    return copysignf(r, x);
}
// f32 -> bf16 bits, round-to-nearest-even (finite inputs)
__device__ __forceinline__ unsigned short f2bf(float x) {
    u32 u = __float_as_uint(x);
    return (unsigned short)((u + 0x7fffu + ((u >> 16) & 1u)) >> 16);
}
__device__ __forceinline__ float bf2f(unsigned short s) {
    return __uint_as_float(((u32)s) << 16);
}
__device__ __forceinline__ float bf_lo32(u32 u) { return __uint_as_float(u << 16); }
__device__ __forceinline__ float bf_hi32(u32 u) { return __uint_as_float(u & 0xffff0000u); }

// ---------------------------------------------------------------------------
// Convert + SWIZZLE weights into MFMA B-fragment order (bf16):
// out[((jr*4+kc)*64 + l)*8 + i] = W[(jr*16 + (l&15))*H + kc*32 + (l>>4)*8 + i]
// ---------------------------------------------------------------------------
__global__ __launch_bounds__(256) void convert_w_kernel(
    const float* __restrict__ Wih, const float* __restrict__ Whh,
    const float* __restrict__ Wm,
    unsigned short* __restrict__ Wihs, unsigned short* __restrict__ Whhs,
    unsigned short* __restrict__ Wms)
{
    int idx = blockIdx.x * 256 + threadIdx.x;   // chunk-lane id
    if (idx >= 6144) return;
    int l  = idx & 63;
    int kc = (idx >> 6) & 3;
    int jr = idx >> 8;
    int m = l & 15, q = l >> 4;
    size_t srco = (size_t)(jr * 16 + m) * H + kc * 32 + q * 8;

    {
        const float4* s0 = (const float4*)(Wih + srco);
        float4 a = s0[0], b = s0[1];
        short8 v;
        v[0] = (short)f2bf(a.x); v[1] = (short)f2bf(a.y);
        v[2] = (short)f2bf(a.z); v[3] = (short)f2bf(a.w);
        v[4] = (short)f2bf(b.x); v[5] = (short)f2bf(b.y);
        v[6] = (short)f2bf(b.z); v[7] = (short)f2bf(b.w);
        *(short8*)(Wihs + (size_t)idx * 8) = v;
    }
    {
        const float4* s0 = (const float4*)(Whh + srco);
        float4 a = s0[0], b = s0[1];
        short8 v;
        v[0] = (short)f2bf(a.x); v[1] = (short)f2bf(a.y);
        v[2] = (short)f2bf(a.z); v[3] = (short)f2bf(a.w);
        v[4] = (short)f2bf(b.x); v[5] = (short)f2bf(b.y);
        v[6] = (short)f2bf(b.z); v[7] = (short)f2bf(b.w);
        *(short8*)(Whhs + (size_t)idx * 8) = v;
    }
    if (idx < 2048) {
        const float4* s0 = (const float4*)(Wm + srco);
        float4 a = s0[0], b = s0[1];
        short8 v;
        v[0] = (short)f2bf(a.x); v[1] = (short)f2bf(a.y);
        v[2] = (short)f2bf(a.z); v[3] = (short)f2bf(a.w);
        v[4] = (short)f2bf(b.x); v[5] = (short)f2bf(b.y);
        v[6] = (short)f2bf(b.z); v[7] = (short)f2bf(b.w);
        *(short8*)(Wms + (size_t)idx * 8) = v;
    }
}

// ---------------------------------------------------------------------------
// CSR build step 1: degree histogram over dst.
// ---------------------------------------------------------------------------
__global__ __launch_bounds__(256) void hist_kernel(
    const int* __restrict__ eidx, int* __restrict__ deg, int E)
{
    int e = blockIdx.x * 256 + threadIdx.x;
    if (e < E) atomicAdd(&deg[eidx[E + e]], 1);
}

// ---------------------------------------------------------------------------
// CSR build step 2a: per-thread chunk sums + per-block totals (parallel).
// ---------------------------------------------------------------------------
__global__ __launch_bounds__(SCAN_T) void scan_part_kernel(
    const int* __restrict__ deg, int* __restrict__ tsum,
    int* __restrict__ bsum, int N, int ipt)
{
    __shared__ int red[SCAN_T];
    int t = threadIdx.x;
    int g = blockIdx.x * SCAN_T + t;
    int s = g * ipt;
    int e = s + ipt < N ? s + ipt : N;
    int sum = 0;
    for (int i = s; i < e; ++i) sum += deg[i];
    tsum[g] = sum;
    red[t] = sum;
    __syncthreads();
    for (int d = SCAN_T / 2; d > 0; d >>= 1) {
        if (t < d) red[t] += red[t + d];
        __syncthreads();
    }
    if (t == 0) bsum[blockIdx.x] = red[0];
}

// ---------------------------------------------------------------------------
// CSR build step 2b (merged): per-block scan of raw bsum + thread sums,
// then write off/pos. Block 0 also writes off[N].
// ---------------------------------------------------------------------------
__global__ __launch_bounds__(SCAN_T) void scan_final_kernel(
    const int* __restrict__ deg, const int* __restrict__ tsum,
    const int* __restrict__ bsum, int* __restrict__ off,
    int* __restrict__ pos, int N, int ipt)
{
    __shared__ int part[SCAN_T];
    __shared__ int bpre[SCAN_B + 1];
    int t = threadIdx.x;
    if (t == 0) {
        int acc = 0;
        for (int b2 = 0; b2 < SCAN_B; ++b2) { bpre[b2] = acc; acc += bsum[b2]; }
        bpre[SCAN_B] = acc;
        if (blockIdx.x == 0) off[N] = acc;
    }
    int g = blockIdx.x * SCAN_T + t;
    part[t] = tsum[g];
    __syncthreads();
    for (int d = 1; d < SCAN_T; d <<= 1) {
        int v = (t >= d) ? part[t - d] : 0;
        __syncthreads();
        part[t] += v;
        __syncthreads();
    }
    int base = bpre[blockIdx.x] + ((t == 0) ? 0 : part[t - 1]);
    int s = g * ipt;
    int e = s + ipt < N ? s + ipt : N;
    for (int i = s; i < e; ++i) {
        off[i] = base;
        pos[i] = base;
        base += deg[i];
    }
}

// ---------------------------------------------------------------------------
// CSR build step 3: scatter edge ids into slots; pack src|type into one int.
// ---------------------------------------------------------------------------
__global__ __launch_bounds__(256) void fill_kernel(
    const int* __restrict__ eidx, const int* __restrict__ etype,
    int* __restrict__ pos, int* __restrict__ packed, int E)
{
    int e = blockIdx.x * 256 + threadIdx.x;
    if (e >= E) return;
    int src = eidx[e];
    int dst = eidx[E + e];
    int t = etype[e];
    t = t < 0 ? 0 : (t > 8 ? 8 : t);
    int p = atomicAdd(&pos[dst], 1);
    packed[p] = src | (t << 24);
}

// ---------------------------------------------------------------------------
// Kernel A (MFMA): Xh[n][c] = sum_k h[n][k] * Wm[c][k] + bm[c] -> bf16 out.
// Column-split: 2 blocks per 64-node tile; jhalf = blockIdx.x & 1 handles
// j-tiles [jhalf*4, jhalf*4+4). Doubles grid for occupancy.
// ---------------------------------------------------------------------------
__global__ __launch_bounds__(256) void xh_mfma_kernel(
    const float* __restrict__ h, const unsigned short* __restrict__ Wms,
    const float* __restrict__ bm, unsigned short* __restrict__ Xh_b, int N)
{
    __shared__ unsigned short hsb[64 * XS_STRIDE];

    int tid = threadIdx.x;
    int node0 = (blockIdx.x >> 1) * 64;
    int jhalf = blockIdx.x & 1;

    for (int c = tid; c < 1024; c += 256) {
        int r = c >> 4;
        int k8 = (c & 15) << 3;
        int n = node0 + r;
        int nc = n < N ? n : N - 1;
        const float4* hp = (const float4*)(h + (size_t)nc * H + k8);
        float4 a = hp[0], b = hp[1];
        short8 v;
        v[0] = (short)f2bf(a.x); v[1] = (short)f2bf(a.y);
        v[2] = (short)f2bf(a.z); v[3] = (short)f2bf(a.w);
        v[4] = (short)f2bf(b.x); v[5] = (short)f2bf(b.y);
        v[6] = (short)f2bf(b.z); v[7] = (short)f2bf(b.w);
        *(short8*)(&hsb[r * XS_STRIDE + k8]) = v;
    }
    __syncthreads();

    int lane = tid & 63;
    int wv = tid >> 6;
    int am = lane & 15;
    int aq = lane >> 4;

    short8 ah[4];
    int arow = wv * 16 + am;
#pragma unroll
    for (int kc = 0; kc < 4; ++kc)
        ah[kc] = *(const short8*)(&hsb[arow * XS_STRIDE + kc * 32 + aq * 8]);

    floatx4 zero = {0.f, 0.f, 0.f, 0.f};
#pragma unroll
    for (int jt = 0; jt < 4; ++jt) {
        int j = jhalf * 4 + jt;
        floatx4 acc = zero;
#pragma unroll
        for (int kc = 0; kc < 4; ++kc) {
            short8 b = *(const short8*)(Wms + (size_t)(((j * 4 + kc) * 64 + lane)) * 8);
            acc = __builtin_amdgcn_mfma_f32_16x16x32_bf16(ah[kc], b, acc, 0, 0, 0);
        }
        int c = j * 16 + am;
        float bias = bm[c];
#pragma unroll
        for (int q = 0; q < 4; ++q) {
            int node = node0 + wv * 16 + aq * 4 + q;
            if (node < N) Xh_b[(size_t)node * H + c] = f2bf(acc[q] + bias);
        }
    }
}

// ---------------------------------------------------------------------------
// Kernel B (CSR gather): messages[n] = sum_{e: dst=n} Xh[src_e] + emb[type_e]
// 4x unrolled edge loop; emb via packed 7-bit type counters.
// ---------------------------------------------------------------------------
__global__ __launch_bounds__(256) void gather_kernel(
    const unsigned short* __restrict__ Xh_b, const float* __restrict__ emb,
    const int* __restrict__ off, const int* __restrict__ packed,
    unsigned short* __restrict__ messages_b, int N)
{
    int n = blockIdx.x * 4 + (threadIdx.x >> 6);
    if (n >= N) return;
    int lane = threadIdx.x & 63;
    int b = off[n], e = off[n + 1];
    float ax = 0.f, ay = 0.f;
    u64 cnt = 0;
    int i = b;
    for (; i + 4 <= e; i += 4) {
        int u0 = packed[i + 0];
        int u1 = packed[i + 1];
        int u2 = packed[i + 2];
        int u3 = packed[i + 3];
        u32 x0 = *((const u32*)(Xh_b + (size_t)(u0 & 0xffffff) * H) + lane);
        u32 x1 = *((const u32*)(Xh_b + (size_t)(u1 & 0xffffff) * H) + lane);
        u32 x2 = *((const u32*)(Xh_b + (size_t)(u2 & 0xffffff) * H) + lane);
        u32 x3 = *((const u32*)(Xh_b + (size_t)(u3 & 0xffffff) * H) + lane);
        cnt += (1ull << (7 * (u0 >> 24))) + (1ull << (7 * (u1 >> 24)))
             + (1ull << (7 * (u2 >> 24))) + (1ull << (7 * (u3 >> 24)));
        ax += bf_lo32(x0) + bf_lo32(x1) + bf_lo32(x2) + bf_lo32(x3);
        ay += bf_hi32(x0) + bf_hi32(x1) + bf_hi32(x2) + bf_hi32(x3);
    }
    for (; i < e; ++i) {
        int u = packed[i];
        u32 x = *((const u32*)(Xh_b + (size_t)(u & 0xffffff) * H) + lane);
        cnt += 1ull << (7 * (u >> 24));
        ax += bf_lo32(x);
        ay += bf_hi32(x);
    }
#pragma unroll
    for (int t = 0; t < 9; ++t) {
        float c = (float)((u32)(cnt >> (7 * t)) & 127u);
        const float2 ev = *((const float2*)(emb + (size_t)t * H) + lane);
        ax += c * ev.x;
        ay += c * ev.y;
    }
    u32 o = (u32)f2bf(ax) | ((u32)f2bf(ay) << 16);
    *((u32*)(messages_b + (size_t)n * H) + lane) = o;
}

// ---------------------------------------------------------------------------
// Kernel C (MFMA): fused GRU, column-split like xh: 2 blocks per node tile,
// each handles 4 j-tiles (all 3 gates per column -> epilogue stays local).
// ---------------------------------------------------------------------------
__global__ __launch_bounds__(256) void gru_mfma_kernel(
    const unsigned short* __restrict__ messages_b, const float* __restrict__ h,
    const unsigned short* __restrict__ Wihs, const unsigned short* __restrict__ Whhs,
    const float* __restrict__ bih, const float* __restrict__ bhh,
    const int* __restrict__ numn, float* __restrict__ out, int N)
{
    __shared__ unsigned short xs[64 * XS_STRIDE];
    __shared__ unsigned short hsb[64 * XS_STRIDE];

    int tid = threadIdx.x;
    int node0 = (blockIdx.x >> 1) * 64;
    int jhalf = blockIdx.x & 1;

    for (int c = tid; c < 1024; c += 256) {
        int r = c >> 4;
        int k8 = (c & 15) << 3;
        int n = node0 + r;
        int nc = n < N ? n : N - 1;
        short8 xv = *(const short8*)(messages_b + (size_t)nc * H + k8);
        const float4* hp = (const float4*)(h + (size_t)nc * H + k8);
        float4 h0 = hp[0], h1 = hp[1];
        short8 hv;
        hv[0] = (short)f2bf(h0.x); hv[1] = (short)f2bf(h0.y);
        hv[2] = (short)f2bf(h0.z); hv[3] = (short)f2bf(h0.w);
        hv[4] = (short)f2bf(h1.x); hv[5] = (short)f2bf(h1.y);
        hv[6] = (short)f2bf(h1.z); hv[7] = (short)f2bf(h1.w);
        *(short8*)(&xs[r * XS_STRIDE + k8]) = xv;
        *(short8*)(&hsb[r * XS_STRIDE + k8]) = hv;
    }
    __syncthreads();

    int lane = tid & 63;
    int wv = tid >> 6;
    int am = lane & 15;
    int aq = lane >> 4;

    short8 ax[4], ahf[4];
    int arow = wv * 16 + am;
#pragma unroll
    for (int kc = 0; kc < 4; ++kc) {
        ax[kc]  = *(const short8*)(&xs[arow * XS_STRIDE + kc * 32 + aq * 8]);
        ahf[kc] = *(const short8*)(&hsb[arow * XS_STRIDE + kc * 32 + aq * 8]);
    }

    int num_nodes = numn[0];
    floatx4 zero = {0.f, 0.f, 0.f, 0.f};

#pragma unroll
    for (int jt = 0; jt < 4; ++jt) {
        int j = jhalf * 4 + jt;
        floatx4 aIr = zero, aHr = zero, aIz = zero, aHz = zero, aIn = zero, aHn = zero;
#pragma unroll
        for (int kc = 0; kc < 4; ++kc) {
            size_t c_r = (size_t)(((0 * 8 + j) * 4 + kc) * 64 + lane) * 8;
            size_t c_z = (size_t)(((1 * 8 + j) * 4 + kc) * 64 + lane) * 8;
            size_t c_n = (size_t)(((2 * 8 + j) * 4 + kc) * 64 + lane) * 8;
            short8 bir = *(const short8*)(Wihs + c_r);
            short8 bhr = *(const short8*)(Whhs + c_r);
            short8 biz = *(const short8*)(Wihs + c_z);
            short8 bhz = *(const short8*)(Whhs + c_z);
            short8 bin = *(const short8*)(Wihs + c_n);
            short8 bhn = *(const short8*)(Whhs + c_n);
            aIr = __builtin_amdgcn_mfma_f32_16x16x32_bf16(ax[kc],  bir, aIr, 0, 0, 0);
            aHr = __builtin_amdgcn_mfma_f32_16x16x32_bf16(ahf[kc], bhr, aHr, 0, 0, 0);
            aIz = __builtin_amdgcn_mfma_f32_16x16x32_bf16(ax[kc],  biz, aIz, 0, 0, 0);
            aHz = __builtin_amdgcn_mfma_f32_16x16x32_bf16(ahf[kc], bhz, aHz, 0, 0, 0);
            aIn = __builtin_amdgcn_mfma_f32_16x16x32_bf16(ax[kc],  bin, aIn, 0, 0, 0);
            aHn = __builtin_amdgcn_mfma_f32_16x16x32_bf16(ahf[kc], bhn, aHn, 0, 0, 0);
        }
        int c = j * 16 + am;
        float b_ir = bih[c],       b_hr = bhh[c];
        float b_iz = bih[128 + c], b_hz = bhh[128 + c];
        float b_in = bih[256 + c], b_hn = bhh[256 + c];
#pragma unroll
        for (int q = 0; q < 4; ++q) {
            int m = aq * 4 + q;
            int node = node0 + wv * 16 + m;
            if (node < N) {
                float r  = sigmoid_f(aIr[q] + b_ir + aHr[q] + b_hr);
                float z  = sigmoid_f(aIz[q] + b_iz + aHz[q] + b_hz);
                float nv = tanh_f((aIn[q] + b_in) + r * (aHn[q] + b_hn));
                float hv = bf2f(hsb[(wv * 16 + m) * XS_STRIDE + c]);
                float o  = (1.0f - z) * nv + z * hv;
                out[(size_t)node * H + c] = (node < num_nodes) ? o : 0.0f;
            }
        }
    }
}

extern "C" void kernel_launch(void* const* d_in, const int* in_sizes, int n_in,
                              void* d_out, int out_size, void* d_ws, size_t ws_size,
                              hipStream_t stream) {
    const float* h    = (const float*)d_in[0];
    const int*  eidx  = (const int*)d_in[1];
    const int*  etype = (const int*)d_in[2];
    const int*  numn  = (const int*)d_in[3];
    const float* Wm   = (const float*)d_in[4];
    const float* bm   = (const float*)d_in[5];
    const float* emb  = (const float*)d_in[6];
    const float* Wih  = (const float*)d_in[7];
    const float* Whh  = (const float*)d_in[8];
    const float* bih  = (const float*)d_in[9];
    const float* bhh  = (const float*)d_in[10];

    int N = in_sizes[0] / H;
    int E = in_sizes[2];

    // ws layout:
    unsigned short* messages_b = (unsigned short*)d_ws;          // N*H bf16
    unsigned short* Wihs = messages_b + (size_t)N * H;           // 3*H*H (swizzled)
    unsigned short* Whhs = Wihs + 3 * H * H;                     // 3*H*H (swizzled)
    unsigned short* Wms  = Whhs + 3 * H * H;                     // H*H   (swizzled)
    int* deg    = (int*)(Wms + H * H);                           // N
    int* pos    = deg + N;                                       // N
    int* off    = pos + N;                                       // N+1
    int* packed = off + (N + 1);                                 // E
    int* tsum   = packed + E;                                    // SCAN_B*SCAN_T
    int* bsum   = tsum + SCAN_B * SCAN_T;                        // SCAN_B
    unsigned short* Xh_b = (unsigned short*)d_out;               // N*H bf16 scratch in d_out

    hipMemsetAsync(deg, 0, (size_t)N * sizeof(int), stream);

    convert_w_kernel<<<24, 256, 0, stream>>>(Wih, Whh, Wm, Wihs, Whhs, Wms);
    hist_kernel<<<(E + 255) / 256, 256, 0, stream>>>(eidx, deg, E);

    int ipt = (N + SCAN_B * SCAN_T - 1) / (SCAN_B * SCAN_T);
    scan_part_kernel<<<SCAN_B, SCAN_T, 0, stream>>>(deg, tsum, bsum, N, ipt);
    scan_final_kernel<<<SCAN_B, SCAN_T, 0, stream>>>(deg, tsum, bsum, off, pos, N, ipt);

    fill_kernel<<<(E + 255) / 256, 256, 0, stream>>>(eidx, etype, pos, packed, E);

    int nblk = (N + 63) / 64;
    xh_mfma_kernel<<<nblk * 2, 256, 0, stream>>>(h, Wms, bm, Xh_b, N);
    gather_kernel<<<(N + 3) / 4, 256, 0, stream>>>(Xh_b, emb, off, packed, messages_b, N);
    gru_mfma_kernel<<<nblk * 2, 256, 0, stream>>>(messages_b, h, Wihs, Whhs, bih, bhh,
                                                  numn, (float*)d_out, N);
}

// Round 12
// 245.791 us; speedup vs baseline: 8.3527x; 1.0148x over previous
//
#include <hip/hip_runtime.h>
#include <math.h>

#define H 128
typedef unsigned int u32;
typedef unsigned long long u64;
typedef __attribute__((ext_vector_type(8))) short short8;
typedef __attribute__((ext_vector_type(4))) float floatx4;

#define XS_STRIDE 136   // bf16 elems per padded row (128 + 8)

#define SCAN_B 64
#define SCAN_T 256

__device__ __forceinline__ float sigmoid_f(float x) {
    return 1.0f / (1.0f + __expf(-x));
}
__device__ __forceinline__ float tanh_f(float x) {
    float t = __expf(-2.0f * fabsf(x));
    float r = (1.0f - t) / (1.0f + t);
    return copysignf(r, x);
}
// f32 -> bf16 bits, round-to-nearest-even (finite inputs)
__device__ __forceinline__ unsigned short f2bf(float x) {
    u32 u = __float_as_uint(x);
    return (unsigned short)((u + 0x7fffu + ((u >> 16) & 1u)) >> 16);
}
__device__ __forceinline__ float bf2f(unsigned short s) {
    return __uint_as_float(((u32)s) << 16);
}
__device__ __forceinline__ float bf_lo32(u32 u) { return __uint_as_float(u << 16); }
__device__ __forceinline__ float bf_hi32(u32 u) { return __uint_as_float(u & 0xffff0000u); }

// ---------------------------------------------------------------------------
// h (f32) -> h_b (bf16), streaming. One thread = 8 elements.
// ---------------------------------------------------------------------------
__global__ __launch_bounds__(256) void h_convert_kernel(
    const float* __restrict__ h, unsigned short* __restrict__ h_b, int total8)
{
    int idx = blockIdx.x * 256 + threadIdx.x;
    if (idx >= total8) return;
    const float4* p = (const float4*)(h + (size_t)idx * 8);
    float4 a = p[0], b = p[1];
    short8 v;
    v[0] = (short)f2bf(a.x); v[1] = (short)f2bf(a.y);
    v[2] = (short)f2bf(a.z); v[3] = (short)f2bf(a.w);
    v[4] = (short)f2bf(b.x); v[5] = (short)f2bf(b.y);
    v[6] = (short)f2bf(b.z); v[7] = (short)f2bf(b.w);
    *(short8*)(h_b + (size_t)idx * 8) = v;
}

// ---------------------------------------------------------------------------
// Convert + SWIZZLE weights into MFMA B-fragment order (bf16):
// out[((jr*4+kc)*64 + l)*8 + i] = W[(jr*16 + (l&15))*H + kc*32 + (l>>4)*8 + i]
// ---------------------------------------------------------------------------
__global__ __launch_bounds__(256) void convert_w_kernel(
    const float* __restrict__ Wih, const float* __restrict__ Whh,
    const float* __restrict__ Wm,
    unsigned short* __restrict__ Wihs, unsigned short* __restrict__ Whhs,
    unsigned short* __restrict__ Wms)
{
    int idx = blockIdx.x * 256 + threadIdx.x;   // chunk-lane id
    if (idx >= 6144) return;
    int l  = idx & 63;
    int kc = (idx >> 6) & 3;
    int jr = idx >> 8;
    int m = l & 15, q = l >> 4;
    size_t srco = (size_t)(jr * 16 + m) * H + kc * 32 + q * 8;

    {
        const float4* s0 = (const float4*)(Wih + srco);
        float4 a = s0[0], b = s0[1];
        short8 v;
        v[0] = (short)f2bf(a.x); v[1] = (short)f2bf(a.y);
        v[2] = (short)f2bf(a.z); v[3] = (short)f2bf(a.w);
        v[4] = (short)f2bf(b.x); v[5] = (short)f2bf(b.y);
        v[6] = (short)f2bf(b.z); v[7] = (short)f2bf(b.w);
        *(short8*)(Wihs + (size_t)idx * 8) = v;
    }
    {
        const float4* s0 = (const float4*)(Whh + srco);
        float4 a = s0[0], b = s0[1];
        short8 v;
        v[0] = (short)f2bf(a.x); v[1] = (short)f2bf(a.y);
        v[2] = (short)f2bf(a.z); v[3] = (short)f2bf(a.w);
        v[4] = (short)f2bf(b.x); v[5] = (short)f2bf(b.y);
        v[6] = (short)f2bf(b.z); v[7] = (short)f2bf(b.w);
        *(short8*)(Whhs + (size_t)idx * 8) = v;
    }
    if (idx < 2048) {
        const float4* s0 = (const float4*)(Wm + srco);
        float4 a = s0[0], b = s0[1];
        short8 v;
        v[0] = (short)f2bf(a.x); v[1] = (short)f2bf(a.y);
        v[2] = (short)f2bf(a.z); v[3] = (short)f2bf(a.w);
        v[4] = (short)f2bf(b.x); v[5] = (short)f2bf(b.y);
        v[6] = (short)f2bf(b.z); v[7] = (short)f2bf(b.w);
        *(short8*)(Wms + (size_t)idx * 8) = v;
    }
}

// ---------------------------------------------------------------------------
// CSR build step 1: degree histogram over dst.
// ---------------------------------------------------------------------------
__global__ __launch_bounds__(256) void hist_kernel(
    const int* __restrict__ eidx, int* __restrict__ deg, int E)
{
    int e = blockIdx.x * 256 + threadIdx.x;
    if (e < E) atomicAdd(&deg[eidx[E + e]], 1);
}

// ---------------------------------------------------------------------------
// CSR build step 2a: per-thread chunk sums + per-block totals (parallel).
// ---------------------------------------------------------------------------
__global__ __launch_bounds__(SCAN_T) void scan_part_kernel(
    const int* __restrict__ deg, int* __restrict__ tsum,
    int* __restrict__ bsum, int N, int ipt)
{
    __shared__ int red[SCAN_T];
    int t = threadIdx.x;
    int g = blockIdx.x * SCAN_T + t;
    int s = g * ipt;
    int e = s + ipt < N ? s + ipt : N;
    int sum = 0;
    for (int i = s; i < e; ++i) sum += deg[i];
    tsum[g] = sum;
    red[t] = sum;
    __syncthreads();
    for (int d = SCAN_T / 2; d > 0; d >>= 1) {
        if (t < d) red[t] += red[t + d];
        __syncthreads();
    }
    if (t == 0) bsum[blockIdx.x] = red[0];
}

// ---------------------------------------------------------------------------
// CSR build step 2b (merged): per-block scan of raw bsum + thread sums,
// then write off/pos. Block 0 also writes off[N].
// ---------------------------------------------------------------------------
__global__ __launch_bounds__(SCAN_T) void scan_final_kernel(
    const int* __restrict__ deg, const int* __restrict__ tsum,
    const int* __restrict__ bsum, int* __restrict__ off,
    int* __restrict__ pos, int N, int ipt)
{
    __shared__ int part[SCAN_T];
    __shared__ int bpre[SCAN_B + 1];
    int t = threadIdx.x;
    if (t == 0) {
        int acc = 0;
        for (int b2 = 0; b2 < SCAN_B; ++b2) { bpre[b2] = acc; acc += bsum[b2]; }
        bpre[SCAN_B] = acc;
        if (blockIdx.x == 0) off[N] = acc;
    }
    int g = blockIdx.x * SCAN_T + t;
    part[t] = tsum[g];
    __syncthreads();
    for (int d = 1; d < SCAN_T; d <<= 1) {
        int v = (t >= d) ? part[t - d] : 0;
        __syncthreads();
        part[t] += v;
        __syncthreads();
    }
    int base = bpre[blockIdx.x] + ((t == 0) ? 0 : part[t - 1]);
    int s = g * ipt;
    int e = s + ipt < N ? s + ipt : N;
    for (int i = s; i < e; ++i) {
        off[i] = base;
        pos[i] = base;
        base += deg[i];
    }
}

// ---------------------------------------------------------------------------
// CSR build step 3: scatter edge ids into slots; pack src|type into one int.
// ---------------------------------------------------------------------------
__global__ __launch_bounds__(256) void fill_kernel(
    const int* __restrict__ eidx, const int* __restrict__ etype,
    int* __restrict__ pos, int* __restrict__ packed, int E)
{
    int e = blockIdx.x * 256 + threadIdx.x;
    if (e >= E) return;
    int src = eidx[e];
    int dst = eidx[E + e];
    int t = etype[e];
    t = t < 0 ? 0 : (t > 8 ? 8 : t);
    int p = atomicAdd(&pos[dst], 1);
    packed[p] = src | (t << 24);
}

// ---------------------------------------------------------------------------
// Kernel A (MFMA): Xh[n][c] = sum_k h[n][k] * Wm[c][k] + bm[c] -> bf16 out.
// 32-node tiles; wave w: rows (w&1)*16.., j-tiles (w>>1)*4.. (4 of 8).
// h pre-converted to bf16 -> staging is a straight copy.
// ---------------------------------------------------------------------------
__global__ __launch_bounds__(256, 4) void xh_mfma_kernel(
    const unsigned short* __restrict__ h_b, const unsigned short* __restrict__ Wms,
    const float* __restrict__ bm, unsigned short* __restrict__ Xh_b, int N)
{
    __shared__ unsigned short hsb[32 * XS_STRIDE];

    int tid = threadIdx.x;
    int node0 = blockIdx.x * 32;

    for (int c = tid; c < 512; c += 256) {
        int r = c >> 4;
        int k8 = (c & 15) << 3;
        int n = node0 + r;
        int nc = n < N ? n : N - 1;
        *(short8*)(&hsb[r * XS_STRIDE + k8]) =
            *(const short8*)(h_b + (size_t)nc * H + k8);
    }
    __syncthreads();

    int lane = tid & 63;
    int wv = tid >> 6;
    int rg = wv & 1;          // row half
    int jhalf = wv >> 1;      // column half
    int am = lane & 15;
    int aq = lane >> 4;

    short8 ah[4];
    int arow = rg * 16 + am;
#pragma unroll
    for (int kc = 0; kc < 4; ++kc)
        ah[kc] = *(const short8*)(&hsb[arow * XS_STRIDE + kc * 32 + aq * 8]);

    floatx4 zero = {0.f, 0.f, 0.f, 0.f};
#pragma unroll
    for (int jt = 0; jt < 4; ++jt) {
        int j = jhalf * 4 + jt;
        floatx4 acc = zero;
#pragma unroll
        for (int kc = 0; kc < 4; ++kc) {
            short8 b = *(const short8*)(Wms + (size_t)(((j * 4 + kc) * 64 + lane)) * 8);
            acc = __builtin_amdgcn_mfma_f32_16x16x32_bf16(ah[kc], b, acc, 0, 0, 0);
        }
        int c = j * 16 + am;
        float bias = bm[c];
#pragma unroll
        for (int q = 0; q < 4; ++q) {
            int node = node0 + rg * 16 + aq * 4 + q;
            if (node < N) Xh_b[(size_t)node * H + c] = f2bf(acc[q] + bias);
        }
    }
}

// ---------------------------------------------------------------------------
// Kernel B (CSR gather): messages[n] = sum_{e: dst=n} Xh[src_e] + emb[type_e]
// 4x unrolled edge loop; emb via packed 7-bit type counters.
// ---------------------------------------------------------------------------
__global__ __launch_bounds__(256) void gather_kernel(
    const unsigned short* __restrict__ Xh_b, const float* __restrict__ emb,
    const int* __restrict__ off, const int* __restrict__ packed,
    unsigned short* __restrict__ messages_b, int N)
{
    int n = blockIdx.x * 4 + (threadIdx.x >> 6);
    if (n >= N) return;
    int lane = threadIdx.x & 63;
    int b = off[n], e = off[n + 1];
    float ax = 0.f, ay = 0.f;
    u64 cnt = 0;
    int i = b;
    for (; i + 4 <= e; i += 4) {
        int u0 = packed[i + 0];
        int u1 = packed[i + 1];
        int u2 = packed[i + 2];
        int u3 = packed[i + 3];
        u32 x0 = *((const u32*)(Xh_b + (size_t)(u0 & 0xffffff) * H) + lane);
        u32 x1 = *((const u32*)(Xh_b + (size_t)(u1 & 0xffffff) * H) + lane);
        u32 x2 = *((const u32*)(Xh_b + (size_t)(u2 & 0xffffff) * H) + lane);
        u32 x3 = *((const u32*)(Xh_b + (size_t)(u3 & 0xffffff) * H) + lane);
        cnt += (1ull << (7 * (u0 >> 24))) + (1ull << (7 * (u1 >> 24)))
             + (1ull << (7 * (u2 >> 24))) + (1ull << (7 * (u3 >> 24)));
        ax += bf_lo32(x0) + bf_lo32(x1) + bf_lo32(x2) + bf_lo32(x3);
        ay += bf_hi32(x0) + bf_hi32(x1) + bf_hi32(x2) + bf_hi32(x3);
    }
    for (; i < e; ++i) {
        int u = packed[i];
        u32 x = *((const u32*)(Xh_b + (size_t)(u & 0xffffff) * H) + lane);
        cnt += 1ull << (7 * (u >> 24));
        ax += bf_lo32(x);
        ay += bf_hi32(x);
    }
#pragma unroll
    for (int t = 0; t < 9; ++t) {
        float c = (float)((u32)(cnt >> (7 * t)) & 127u);
        const float2 ev = *((const float2*)(emb + (size_t)t * H) + lane);
        ax += c * ev.x;
        ay += c * ev.y;
    }
    u32 o = (u32)f2bf(ax) | ((u32)f2bf(ay) << 16);
    *((u32*)(messages_b + (size_t)n * H) + lane) = o;
}

// ---------------------------------------------------------------------------
// Kernel C (MFMA): fused GRU, 32-node tiles; wave = (row half, j half).
// messages & h both pre-bf16 -> staging is two straight copies.
// ---------------------------------------------------------------------------
__global__ __launch_bounds__(256, 4) void gru_mfma_kernel(
    const unsigned short* __restrict__ messages_b, const unsigned short* __restrict__ h_b,
    const unsigned short* __restrict__ Wihs, const unsigned short* __restrict__ Whhs,
    const float* __restrict__ bih, const float* __restrict__ bhh,
    const int* __restrict__ numn, float* __restrict__ out, int N)
{
    __shared__ unsigned short xs[32 * XS_STRIDE];
    __shared__ unsigned short hsb[32 * XS_STRIDE];

    int tid = threadIdx.x;
    int node0 = blockIdx.x * 32;

    for (int c = tid; c < 512; c += 256) {
        int r = c >> 4;
        int k8 = (c & 15) << 3;
        int n = node0 + r;
        int nc = n < N ? n : N - 1;
        *(short8*)(&xs[r * XS_STRIDE + k8]) =
            *(const short8*)(messages_b + (size_t)nc * H + k8);
        *(short8*)(&hsb[r * XS_STRIDE + k8]) =
            *(const short8*)(h_b + (size_t)nc * H + k8);
    }
    __syncthreads();

    int lane = tid & 63;
    int wv = tid >> 6;
    int rg = wv & 1;
    int jhalf = wv >> 1;
    int am = lane & 15;
    int aq = lane >> 4;

    short8 ax[4], ahf[4];
    int arow = rg * 16 + am;
#pragma unroll
    for (int kc = 0; kc < 4; ++kc) {
        ax[kc]  = *(const short8*)(&xs[arow * XS_STRIDE + kc * 32 + aq * 8]);
        ahf[kc] = *(const short8*)(&hsb[arow * XS_STRIDE + kc * 32 + aq * 8]);
    }

    int num_nodes = numn[0];
    floatx4 zero = {0.f, 0.f, 0.f, 0.f};

#pragma unroll
    for (int jt = 0; jt < 4; ++jt) {
        int j = jhalf * 4 + jt;
        floatx4 aIr = zero, aHr = zero, aIz = zero, aHz = zero, aIn = zero, aHn = zero;
#pragma unroll
        for (int kc = 0; kc < 4; ++kc) {
            size_t c_r = (size_t)(((0 * 8 + j) * 4 + kc) * 64 + lane) * 8;
            size_t c_z = (size_t)(((1 * 8 + j) * 4 + kc) * 64 + lane) * 8;
            size_t c_n = (size_t)(((2 * 8 + j) * 4 + kc) * 64 + lane) * 8;
            short8 bir = *(const short8*)(Wihs + c_r);
            short8 bhr = *(const short8*)(Whhs + c_r);
            short8 biz = *(const short8*)(Wihs + c_z);
            short8 bhz = *(const short8*)(Whhs + c_z);
            short8 bin = *(const short8*)(Wihs + c_n);
            short8 bhn = *(const short8*)(Whhs + c_n);
            aIr = __builtin_amdgcn_mfma_f32_16x16x32_bf16(ax[kc],  bir, aIr, 0, 0, 0);
            aHr = __builtin_amdgcn_mfma_f32_16x16x32_bf16(ahf[kc], bhr, aHr, 0, 0, 0);
            aIz = __builtin_amdgcn_mfma_f32_16x16x32_bf16(ax[kc],  biz, aIz, 0, 0, 0);
            aHz = __builtin_amdgcn_mfma_f32_16x16x32_bf16(ahf[kc], bhz, aHz, 0, 0, 0);
            aIn = __builtin_amdgcn_mfma_f32_16x16x32_bf16(ax[kc],  bin, aIn, 0, 0, 0);
            aHn = __builtin_amdgcn_mfma_f32_16x16x32_bf16(ahf[kc], bhn, aHn, 0, 0, 0);
        }
        int c = j * 16 + am;
        float b_ir = bih[c],       b_hr = bhh[c];
        float b_iz = bih[128 + c], b_hz = bhh[128 + c];
        float b_in = bih[256 + c], b_hn = bhh[256 + c];
#pragma unroll
        for (int q = 0; q < 4; ++q) {
            int m = aq * 4 + q;
            int node = node0 + rg * 16 + m;
            if (node < N) {
                float r  = sigmoid_f(aIr[q] + b_ir + aHr[q] + b_hr);
                float z  = sigmoid_f(aIz[q] + b_iz + aHz[q] + b_hz);
                float nv = tanh_f((aIn[q] + b_in) + r * (aHn[q] + b_hn));
                float hv = bf2f(hsb[(rg * 16 + m) * XS_STRIDE + c]);
                float o  = (1.0f - z) * nv + z * hv;
                out[(size_t)node * H + c] = (node < num_nodes) ? o : 0.0f;
            }
        }
    }
}

extern "C" void kernel_launch(void* const* d_in, const int* in_sizes, int n_in,
                              void* d_out, int out_size, void* d_ws, size_t ws_size,
                              hipStream_t stream) {
    const float* h    = (const float*)d_in[0];
    const int*  eidx  = (const int*)d_in[1];
    const int*  etype = (const int*)d_in[2];
    const int*  numn  = (const int*)d_in[3];
    const float* Wm   = (const float*)d_in[4];
    const float* bm   = (const float*)d_in[5];
    const float* emb  = (const float*)d_in[6];
    const float* Wih  = (const float*)d_in[7];
    const float* Whh  = (const float*)d_in[8];
    const float* bih  = (const float*)d_in[9];
    const float* bhh  = (const float*)d_in[10];

    int N = in_sizes[0] / H;
    int E = in_sizes[2];

    // ws layout:
    unsigned short* messages_b = (unsigned short*)d_ws;          // N*H bf16
    unsigned short* h_b  = messages_b + (size_t)N * H;           // N*H bf16
    unsigned short* Wihs = h_b + (size_t)N * H;                  // 3*H*H (swizzled)
    unsigned short* Whhs = Wihs + 3 * H * H;                     // 3*H*H (swizzled)
    unsigned short* Wms  = Whhs + 3 * H * H;                     // H*H   (swizzled)
    int* deg    = (int*)(Wms + H * H);                           // N
    int* pos    = deg + N;                                       // N
    int* off    = pos + N;                                       // N+1
    int* packed = off + (N + 1);                                 // E
    int* tsum   = packed + E;                                    // SCAN_B*SCAN_T
    int* bsum   = tsum + SCAN_B * SCAN_T;                        // SCAN_B
    unsigned short* Xh_b = (unsigned short*)d_out;               // N*H bf16 scratch in d_out

    hipMemsetAsync(deg, 0, (size_t)N * sizeof(int), stream);

    int total8 = N * H / 8;
    h_convert_kernel<<<(total8 + 255) / 256, 256, 0, stream>>>(h, h_b, total8);
    convert_w_kernel<<<24, 256, 0, stream>>>(Wih, Whh, Wm, Wihs, Whhs, Wms);
    hist_kernel<<<(E + 255) / 256, 256, 0, stream>>>(eidx, deg, E);

    int ipt = (N + SCAN_B * SCAN_T - 1) / (SCAN_B * SCAN_T);
    scan_part_kernel<<<SCAN_B, SCAN_T, 0, stream>>>(deg, tsum, bsum, N, ipt);
    scan_final_kernel<<<SCAN_B, SCAN_T, 0, stream>>>(deg, tsum, bsum, off, pos, N, ipt);

    fill_kernel<<<(E + 255) / 256, 256, 0, stream>>>(eidx, etype, pos, packed, E);

    int nblk32 = (N + 31) / 32;
    xh_mfma_kernel<<<nblk32, 256, 0, stream>>>(h_b, Wms, bm, Xh_b, N);
    gather_kernel<<<(N + 3) / 4, 256, 0, stream>>>(Xh_b, emb, off, packed, messages_b, N);
    gru_mfma_kernel<<<nblk32, 256, 0, stream>>>(messages_b, h_b, Wihs, Whhs, bih, bhh,
                                                numn, (float*)d_out, N);
}